// Round 14
// baseline (775.558 us; speedup 1.0000x reference)
//
#include <hip/hip_runtime.h>

typedef __bf16 bf16;
typedef bf16  bf16x8 __attribute__((ext_vector_type(8)));
typedef bf16  bf16x4 __attribute__((ext_vector_type(4)));
typedef float f32x4  __attribute__((ext_vector_type(4)));

#define T_SEQ 2048

__device__ __forceinline__ void gload_lds16(const bf16* g, bf16* l) {
    __builtin_amdgcn_global_load_lds(
        (const __attribute__((address_space(1))) unsigned int*)g,
        (__attribute__((address_space(3))) unsigned int*)l,
        16, 0, 0);
}

#define VMCNT(n) asm volatile("s_waitcnt vmcnt(" #n ")" ::: "memory")
#define BAR() do { asm volatile("" ::: "memory"); __builtin_amdgcn_s_barrier(); \
                   asm volatile("" ::: "memory"); } while (0)

// ---------------------------------------------------------------------------
// Tiled transpose fp32 [R][Cc] -> bf16 [Cc][R], batched on z.
// ---------------------------------------------------------------------------
__global__ __launch_bounds__(256) void transpose_f32_bf16(
    const float* __restrict__ in, bf16* __restrict__ out, int R, int Cc, int ldo)
{
    __shared__ float tile[32][33];
    const int bx = blockIdx.x * 32;
    const int by = blockIdx.y * 32;
    const long bi = (long)blockIdx.z * R * Cc;
    const long bo = (long)blockIdx.z * Cc * ldo;
    const int tx = threadIdx.x, ty = threadIdx.y;
#pragma unroll
    for (int i = 0; i < 4; ++i)
        tile[ty + i * 8][tx] = in[bi + (long)(by + ty + i * 8) * Cc + bx + tx];
    __syncthreads();
#pragma unroll
    for (int i = 0; i < 4; ++i)
        out[bo + (long)(bx + ty + i * 8) * ldo + by + tx] = (bf16)tile[tx][ty + i * 8];
}

// ---------------------------------------------------------------------------
// Tiled transpose bf16 [rows][ldi] -> bf16 [cols][ldo] (for V^T).
// ---------------------------------------------------------------------------
__global__ __launch_bounds__(256) void transpose_bf16(
    const bf16* __restrict__ in, bf16* __restrict__ out, int ldi, int ldo)
{
    __shared__ bf16 tile[32][33];
    const int bx = blockIdx.x * 32;
    const int by = blockIdx.y * 32;
    const int tx = threadIdx.x, ty = threadIdx.y;
#pragma unroll
    for (int i = 0; i < 4; ++i)
        tile[ty + i * 8][tx] = in[(long)(by + ty + i * 8) * ldi + bx + tx];
    __syncthreads();
#pragma unroll
    for (int i = 0; i < 4; ++i)
        out[(long)(bx + ty + i * 8) * ldo + by + tx] = tile[tx][ty + i * 8];
}

// ---------------------------------------------------------------------------
// LayerNorm fp32 input -> bf16; and bf16-input variant.
// ---------------------------------------------------------------------------
__global__ __launch_bounds__(256) void ln_kernel(
    const float* __restrict__ x, const float* __restrict__ g,
    const float* __restrict__ bb, bf16* __restrict__ out)
{
    const long row = blockIdx.x;
    const int tid = threadIdx.x;
    const float4 v = ((const float4*)(x + row * 1024))[tid];
    float s  = v.x + v.y + v.z + v.w;
    float s2 = v.x * v.x + v.y * v.y + v.z * v.z + v.w * v.w;
#pragma unroll
    for (int off = 32; off >= 1; off >>= 1) {
        s  += __shfl_xor(s,  off, 64);
        s2 += __shfl_xor(s2, off, 64);
    }
    __shared__ float red[8];
    const int wid = tid >> 6;
    if ((tid & 63) == 0) { red[wid] = s; red[4 + wid] = s2; }
    __syncthreads();
    s  = red[0] + red[1] + red[2] + red[3];
    s2 = red[4] + red[5] + red[6] + red[7];
    const float mu   = s * (1.f / 1024.f);
    const float rstd = rsqrtf(s2 * (1.f / 1024.f) - mu * mu + 1e-5f);
    const float4 gv = ((const float4*)g)[tid];
    const float4 bv = ((const float4*)bb)[tid];
    bf16x4 ov;
    ov[0] = (bf16)((v.x - mu) * rstd * gv.x + bv.x);
    ov[1] = (bf16)((v.y - mu) * rstd * gv.y + bv.y);
    ov[2] = (bf16)((v.z - mu) * rstd * gv.z + bv.z);
    ov[3] = (bf16)((v.w - mu) * rstd * gv.w + bv.w);
    *(bf16x4*)(out + row * 1024 + tid * 4) = ov;
}

__global__ __launch_bounds__(256) void ln_kernel_b(
    const bf16* __restrict__ x, const float* __restrict__ g,
    const float* __restrict__ bb, bf16* __restrict__ out)
{
    const long row = blockIdx.x;
    const int tid = threadIdx.x;
    const bf16x4 vb = ((const bf16x4*)(x + row * 1024))[tid];
    const float v0 = (float)vb[0], v1 = (float)vb[1];
    const float v2 = (float)vb[2], v3 = (float)vb[3];
    float s  = v0 + v1 + v2 + v3;
    float s2 = v0 * v0 + v1 * v1 + v2 * v2 + v3 * v3;
#pragma unroll
    for (int off = 32; off >= 1; off >>= 1) {
        s  += __shfl_xor(s,  off, 64);
        s2 += __shfl_xor(s2, off, 64);
    }
    __shared__ float red[8];
    const int wid = tid >> 6;
    if ((tid & 63) == 0) { red[wid] = s; red[4 + wid] = s2; }
    __syncthreads();
    s  = red[0] + red[1] + red[2] + red[3];
    s2 = red[4] + red[5] + red[6] + red[7];
    const float mu   = s * (1.f / 1024.f);
    const float rstd = rsqrtf(s2 * (1.f / 1024.f) - mu * mu + 1e-5f);
    const float4 gv = ((const float4*)g)[tid];
    const float4 bv = ((const float4*)bb)[tid];
    bf16x4 ov;
    ov[0] = (bf16)((v0 - mu) * rstd * gv.x + bv.x);
    ov[1] = (bf16)((v1 - mu) * rstd * gv.y + bv.y);
    ov[2] = (bf16)((v2 - mu) * rstd * gv.z + bv.z);
    ov[3] = (bf16)((v3 - mu) * rstd * gv.w + bv.w);
    *(bf16x4*)(out + row * 1024 + tid * 4) = ov;
}

// ---------------------------------------------------------------------------
// Shared fragment-load / MFMA macros for the 256-row GEMMs.
// ---------------------------------------------------------------------------
#define LOADA(BUFP, QM) do {                                                   \
    const char* ab_ = (BUFP) + (size_t)((wr * 64 + (QM) * 128 + fr) * 128);    \
    _Pragma("unroll") for (int m_ = 0; m_ < 4; ++m_) {                         \
        af[m_][0] = *(const bf16x8*)(ab_ + m_ * 2048 + so0);                   \
        af[m_][1] = *(const bf16x8*)(ab_ + m_ * 2048 + so1); } } while (0)

#define LOADB(BUFP, QN, DST) do {                                              \
    const char* bb_ = (BUFP) + (size_t)((wc * 32 + (QN) * 128 + fr) * 128);    \
    _Pragma("unroll") for (int n_ = 0; n_ < 2; ++n_) {                         \
        DST[n_][0] = *(const bf16x8*)(bb_ + n_ * 2048 + so0);                  \
        DST[n_][1] = *(const bf16x8*)(bb_ + n_ * 2048 + so1); } } while (0)

#define MMA(ACC, BSET) do { __builtin_amdgcn_s_setprio(1);                     \
    _Pragma("unroll") for (int m_ = 0; m_ < 4; ++m_)                           \
    _Pragma("unroll") for (int n_ = 0; n_ < 2; ++n_) {                         \
        ACC[m_][n_] = __builtin_amdgcn_mfma_f32_16x16x32_bf16(                 \
            af[m_][0], BSET[n_][0], ACC[m_][n_], 0, 0, 0);                     \
        ACC[m_][n_] = __builtin_amdgcn_mfma_f32_16x16x32_bf16(                 \
            af[m_][1], BSET[n_][1], ACC[m_][n_], 0, 0, 0); }                   \
    __builtin_amdgcn_s_setprio(0); } while (0)

// ---------------------------------------------------------------------------
// 256x256 bf16 GEMM (round-8/9 PROVEN): 1.5-tile-ahead + B0 retention.
// ---------------------------------------------------------------------------
#define TB_DEEP(W1N, W3N, ISSN, ISSC) do {                                     \
    const char* abuf = cAs + ((size_t)cur << 15);                              \
    const char* bbuf = cBs + ((size_t)cur << 15);                              \
    const long kb  = (long)(k + 1) * 64;                                       \
    const long kb2 = (long)(k + 2) * 64;                                       \
    LOADA(abuf, 0);                                                            \
    LOADB(bbuf, 0, bfv0);                                                      \
    if (ISSN) stageB(nxt, 0, kb);        /* B0[k+1] */                         \
    BAR(); MMA(a00, bfv0); BAR();                                              \
    LOADB(bbuf, 1, bfv1);                                                      \
    if (ISSN) stageA(nxt, 1, kb);        /* A1[k+1] */                         \
    VMCNT(W1N);                                                                \
    BAR(); MMA(a01, bfv1); BAR();                                              \
    LOADA(abuf, 1);                                                            \
    if (ISSC) stageA(cur, 0, kb2);       /* A0[k+2] */                         \
    BAR(); MMA(a11, bfv1); BAR();                                              \
    if (ISSC) stageB(cur, 1, kb2);       /* B1[k+2] */                         \
    VMCNT(W3N);                                                                \
    BAR(); MMA(a10, bfv0); BAR(); } while (0)

template <int MODE>
__global__ __launch_bounds__(512, 1) void gemm256(
    const bf16* __restrict__ A, const bf16* __restrict__ Bt,
    const float* __restrict__ bias, const float* __restrict__ resid,
    void* __restrict__ outp, int M, int N, int K, int nbn)
{
    extern __shared__ __align__(16) char smem[];
    char* cAs = smem;
    char* cBs = smem + 65536;

    const int tid = threadIdx.x;
    const int wid = tid >> 6, lane = tid & 63;
    const int wr = wid >> 2, wc = wid & 3;
    const int fr = lane & 15, fq = lane >> 4;

    const int nwg = gridDim.x;
    const int cpx = nwg >> 3;
    const int b0  = blockIdx.x;
    const int bid = (b0 & 7) * cpx + (b0 >> 3);
    const long bm = bid / nbn, bn = bid % nbn;
    const long bmrow = bm * 256, bnrow = bn * 256;

    const int srow0 = wid * 8 + (lane >> 3);
    const int sslot = (lane & 7) ^ (lane >> 3);
    auto stageA = [&](int buf, int h, long kt) {
        const bf16* g = A + (size_t)(bmrow + h * 128 + srow0) * K + kt + sslot * 8;
        char* l = cAs + ((size_t)buf << 15) + h * 16384 + (size_t)wid * 1024;
        gload_lds16(g, (bf16*)l);
        gload_lds16(g + (size_t)64 * K, (bf16*)(l + 8192));
    };
    auto stageB = [&](int buf, int h, long kt) {
        const bf16* g = Bt + (size_t)(bnrow + h * 128 + srow0) * K + kt + sslot * 8;
        char* l = cBs + ((size_t)buf << 15) + h * 16384 + (size_t)wid * 1024;
        gload_lds16(g, (bf16*)l);
        gload_lds16(g + (size_t)64 * K, (bf16*)(l + 8192));
    };

    const int sx  = fr & 7;
    const int so0 = ((fq) ^ sx) * 16;
    const int so1 = ((4 + fq) ^ sx) * 16;

    bf16x8 af[4][2], bfv0[2][2], bfv1[2][2];
    f32x4 a00[4][2], a01[4][2], a11[4][2], a10[4][2];
#pragma unroll
    for (int m = 0; m < 4; ++m)
#pragma unroll
        for (int n = 0; n < 2; ++n) {
            a00[m][n] = {0.f, 0.f, 0.f, 0.f}; a01[m][n] = {0.f, 0.f, 0.f, 0.f};
            a11[m][n] = {0.f, 0.f, 0.f, 0.f}; a10[m][n] = {0.f, 0.f, 0.f, 0.f};
        }

    stageA(0, 0, 0);      // A0_0
    stageB(0, 1, 0);      // B1_0
    stageB(0, 0, 0);      // B0_0
    stageA(0, 1, 0);      // A1_0
    stageA(1, 0, 64);     // A0_1
    stageB(1, 1, 64);     // B1_1
    VMCNT(6);
    BAR();

    const int NT = K >> 6;
    int cur, nxt;
    int k = 0;
    for (; k < NT - 2; ++k) {
        cur = k & 1; nxt = cur ^ 1;
        TB_DEEP(8, 6, true, true);
    }
    cur = k & 1; nxt = cur ^ 1;
    TB_DEEP(8, 2, true, false);          // k = NT-2
    ++k;
    cur = k & 1; nxt = cur ^ 1;
    TB_DEEP(0, 0, false, false);         // k = NT-1

    auto writeQ = [&](f32x4 (&acc)[4][2], int QM, int QN) {
#pragma unroll
        for (int m = 0; m < 4; ++m) {
            const long row0 = bmrow + wr * 64 + QM * 128 + m * 16 + fq * 4;
#pragma unroll
            for (int n = 0; n < 2; ++n) {
                const long col = bnrow + wc * 32 + QN * 128 + n * 16 + fr;
                const float bv = (MODE == 0) ? 0.f : bias[col];
#pragma unroll
                for (int j = 0; j < 4; ++j) {
                    const long row = row0 + j;
                    float v = acc[m][n][j] + bv;
                    if (MODE == 1) v = fmaxf(v, 0.f);
                    if (MODE == 2) {
                        v += resid[row * N + col];
                        ((float*)outp)[row * N + col] = v;
                    } else {
                        ((bf16*)outp)[row * N + col] = (bf16)v;
                    }
                }
            }
        }
    };
    writeQ(a00, 0, 0); writeQ(a01, 0, 1); writeQ(a11, 1, 1); writeQ(a10, 1, 0);
}

// ---------------------------------------------------------------------------
// 256x128 bf16 GEMM (PROVEN schedule). MODE: 0 plain->bf16;
// 3 bias+f32resid->bf16; 4 bias+bf16resid->f32.
// ---------------------------------------------------------------------------
#define TILE_BODY_N(PRE, LAST) do {                                            \
    const char* abuf = cAs + ((size_t)cur << 15);                              \
    const char* bbuf = cBs + ((size_t)cur << 14);                              \
    const long kn = (long)(k + 1) * 64;                                        \
    LOADA(abuf, 0);                                                            \
    LOADB(bbuf, 0, bfv);                                                       \
    if (PRE) { stageA(nxt, 0, kn); stageB(nxt, kn); stageA(nxt, 1, kn);        \
               VMCNT(6); }                                                     \
    else     { VMCNT(0); }                                                     \
    BAR(); MMA(aq0, bfv); BAR();                                               \
    LOADA(abuf, 1);                                                            \
    if (PRE) { VMCNT(2); }                                                     \
    if (!LAST) { BAR(); }                                                      \
    MMA(aq1, bfv);                                                             \
    if (!LAST) { BAR(); } } while (0)

template <int MODE>
__global__ __launch_bounds__(512, 2) void gemm256n(
    const bf16* __restrict__ A, const bf16* __restrict__ Bt,
    const float* __restrict__ bias, const void* __restrict__ resid,
    void* __restrict__ outp, int M, int N, int K, int nbn)
{
    extern __shared__ __align__(16) char smem[];
    char* cAs = smem;            // 2 x 32 KiB
    char* cBs = smem + 65536;    // 2 x 16 KiB

    const int tid = threadIdx.x;
    const int wid = tid >> 6, lane = tid & 63;
    const int wr = wid >> 2, wc = wid & 3;
    const int fr = lane & 15, fq = lane >> 4;

    const int nwg = gridDim.x;
    const int cpx = nwg >> 3;
    const int b0  = blockIdx.x;
    const int bid = (b0 & 7) * cpx + (b0 >> 3);
    const long bm = bid / nbn, bn = bid % nbn;
    const long bmrow = bm * 256, bnrow = bn * 128;

    const int srow0 = wid * 8 + (lane >> 3);
    const int sslot = (lane & 7) ^ (lane >> 3);
    auto stageA = [&](int buf, int h, long kt) {
        const bf16* g = A + (size_t)(bmrow + h * 128 + srow0) * K + kt + sslot * 8;
        char* l = cAs + ((size_t)buf << 15) + h * 16384 + (size_t)wid * 1024;
        gload_lds16(g, (bf16*)l);
        gload_lds16(g + (size_t)64 * K, (bf16*)(l + 8192));
    };
    auto stageB = [&](int buf, long kt) {
        const bf16* g = Bt + (size_t)(bnrow + srow0) * K + kt + sslot * 8;
        char* l = cBs + ((size_t)buf << 14) + (size_t)wid * 1024;
        gload_lds16(g, (bf16*)l);
        gload_lds16(g + (size_t)64 * K, (bf16*)(l + 8192));
    };

    const int sx  = fr & 7;
    const int so0 = ((fq) ^ sx) * 16;
    const int so1 = ((4 + fq) ^ sx) * 16;

    bf16x8 af[4][2], bfv[2][2];
    f32x4 aq0[4][2], aq1[4][2];
#pragma unroll
    for (int m = 0; m < 4; ++m)
#pragma unroll
        for (int n = 0; n < 2; ++n) {
            aq0[m][n] = {0.f, 0.f, 0.f, 0.f};
            aq1[m][n] = {0.f, 0.f, 0.f, 0.f};
        }

    stageA(0, 0, 0); stageB(0, 0); stageA(0, 1, 0);
    VMCNT(2);
    BAR();

    const int NT = K >> 6;
    int cur = 0, nxt = 1;
    int k = 0;
    for (; k < NT - 1; ++k) {
        cur = k & 1; nxt = cur ^ 1;
        TILE_BODY_N(true, false);
    }
    cur = k & 1; nxt = cur ^ 1;
    TILE_BODY_N(false, true);

    auto writeQ = [&](f32x4 (&acc)[4][2], int QM) {
#pragma unroll
        for (int m = 0; m < 4; ++m) {
            const long row0 = bmrow + wr * 64 + QM * 128 + m * 16 + fq * 4;
#pragma unroll
            for (int n = 0; n < 2; ++n) {
                const long col = bnrow + wc * 32 + n * 16 + fr;
                const float bv = (MODE == 0) ? 0.f : bias[col];
#pragma unroll
                for (int j = 0; j < 4; ++j) {
                    const long row = row0 + j;
                    float v = acc[m][n][j] + bv;
                    if (MODE == 3) {
                        v += ((const float*)resid)[row * N + col];
                        ((bf16*)outp)[row * N + col] = (bf16)v;
                    } else if (MODE == 4) {
                        v += (float)((const bf16*)resid)[row * N + col];
                        ((float*)outp)[row * N + col] = v;
                    } else {
                        ((bf16*)outp)[row * N + col] = (bf16)v;
                    }
                }
            }
        }
    };
    writeQ(aq0, 0); writeQ(aq1, 1);
}

// ---------------------------------------------------------------------------
// Flash attention v9: PAIRED tiles (round-9 proven structure) + single
// swizzled P[16][64] per wave (layout proven in rounds 11/13).
// LDS = 16K(K) + 16K(V) + 8K(P) = 40960 B exactly -> 4 blocks/CU when
// VGPR <= 128 -> 1024-block grid = one exact dispatch round.
// P write: byte r*128 + ((2c) ^ ((r&7)<<4)); P/V reads swizzled b128.
// ---------------------------------------------------------------------------
__device__ __forceinline__ void sm_part(
    f32x4* s, float* mj, f32x4* o, f32x4& o_l, bf16* Pp,
    int fr, int fq, int qloc, bool diag)
{
    float v[4][4], mxj[4];
#pragma unroll
    for (int j = 0; j < 4; ++j) {
        const int qg = qloc + fq * 4 + j;
        v[0][j] = s[0][j] * 0.03125f;
        v[1][j] = s[1][j] * 0.03125f;
        v[2][j] = s[2][j] * 0.03125f;
        v[3][j] = s[3][j] * 0.03125f;
        if (diag) {
            if (fr      > qg) v[0][j] = -1e30f;
            if (16 + fr > qg) v[1][j] = -1e30f;
            if (32 + fr > qg) v[2][j] = -1e30f;
            if (48 + fr > qg) v[3][j] = -1e30f;
        }
        float mx = fmaxf(fmaxf(v[0][j], v[1][j]), fmaxf(v[2][j], v[3][j]));
#pragma unroll
        for (int off = 1; off <= 8; off <<= 1) mx = fmaxf(mx, __shfl_xor(mx, off, 16));
        mxj[j] = mx;
    }
    float need = fmaxf(fmaxf(mxj[0] - mj[0], mxj[1] - mj[1]),
                       fmaxf(mxj[2] - mj[2], mxj[3] - mj[3]));
    if (__any(need > 8.f)) {
#pragma unroll
        for (int j = 0; j < 4; ++j) {
            const float mn   = fmaxf(mj[j], mxj[j]);
            const float corr = __expf(mj[j] - mn);
            mj[j] = mn;
#pragma unroll
            for (int nd = 0; nd < 4; ++nd) o[nd][j] *= corr;
            o_l[j] *= corr;
        }
    }
#pragma unroll
    for (int j = 0; j < 4; ++j) {
        const int r = fq * 4 + j;
        char* prow = (char*)Pp + r * 128;
        const int sw = (r & 7) << 4;
        *(bf16*)(prow + ((fr * 2) ^ sw))      = (bf16)__expf(v[0][j] - mj[j]);
        *(bf16*)(prow + ((32 + fr * 2) ^ sw)) = (bf16)__expf(v[1][j] - mj[j]);
        *(bf16*)(prow + ((64 + fr * 2) ^ sw)) = (bf16)__expf(v[2][j] - mj[j]);
        *(bf16*)(prow + ((96 + fr * 2) ^ sw)) = (bf16)__expf(v[3][j] - mj[j]);
    }
}

#define PLOAD(P0, P1, PP) do {                                                 \
    const int swr_ = (fr & 7) << 4;                                            \
    P0 = *(const bf16x8*)((const char*)(PP) + fr * 128 + ((fq * 16) ^ swr_));  \
    P1 = *(const bf16x8*)((const char*)(PP) + fr * 128 + ((64 + fq * 16) ^ swr_)); } while (0)

__device__ __forceinline__ void attn_step(
    const bf16* __restrict__ Ks, const bf16* __restrict__ Vt,
    bf16* __restrict__ Pp, const bf16x8* qf,
    f32x4* o, f32x4& o_l, float* mj, const bf16x8 onesf,
    int fr, int fq, int qloc, bool diag)
{
    f32x4 s[4];
#pragma unroll
    for (int n = 0; n < 4; ++n) s[n] = {0.f, 0.f, 0.f, 0.f};
    __builtin_amdgcn_s_setprio(1);
#pragma unroll
    for (int n = 0; n < 4; ++n) {
        const int t  = n * 16 + fr;
        const int sw = ((t ^ (t >> 3)) & 7) << 4;
        const bf16x8 kf0 = *(const bf16x8*)((const char*)Ks + t * 128 + ((fq * 16) ^ sw));
        const bf16x8 kf1 = *(const bf16x8*)((const char*)Ks + t * 128 + ((64 + fq * 16) ^ sw));
        s[n] = __builtin_amdgcn_mfma_f32_16x16x32_bf16(qf[0], kf0, s[n], 0, 0, 0);
        s[n] = __builtin_amdgcn_mfma_f32_16x16x32_bf16(qf[1], kf1, s[n], 0, 0, 0);
    }
    __builtin_amdgcn_s_setprio(0);
    sm_part(s, mj, o, o_l, Pp, fr, fq, qloc, diag);
    asm volatile("s_waitcnt lgkmcnt(0)" ::: "memory");
    __builtin_amdgcn_sched_barrier(0);
    bf16x8 pf0, pf1;
    PLOAD(pf0, pf1, Pp);
    __builtin_amdgcn_s_setprio(1);
#pragma unroll
    for (int nd = 0; nd < 4; ++nd) {
        const int dd = nd * 16 + fr;
        const int sw = ((dd ^ (dd >> 3)) & 7) << 4;
        const bf16x8 vf0 = *(const bf16x8*)((const char*)Vt + dd * 128 + ((fq * 16) ^ sw));
        const bf16x8 vf1 = *(const bf16x8*)((const char*)Vt + dd * 128 + ((64 + fq * 16) ^ sw));
        o[nd] = __builtin_amdgcn_mfma_f32_16x16x32_bf16(pf0, vf0, o[nd], 0, 0, 0);
        o[nd] = __builtin_amdgcn_mfma_f32_16x16x32_bf16(pf1, vf1, o[nd], 0, 0, 0);
    }
    o_l = __builtin_amdgcn_mfma_f32_16x16x32_bf16(pf0, onesf, o_l, 0, 0, 0);
    o_l = __builtin_amdgcn_mfma_f32_16x16x32_bf16(pf1, onesf, o_l, 0, 0, 0);
    __builtin_amdgcn_s_setprio(0);
}

__device__ __forceinline__ void attn_step2(
    const bf16* __restrict__ Ks, const bf16* __restrict__ Vt,
    bf16* __restrict__ Pp,
    const bf16x8* qfA, const bf16x8* qfB,
    f32x4* oA, f32x4& olA, float* mA,
    f32x4* oB, f32x4& olB, float* mB,
    const bf16x8 onesf, int fr, int fq, int qloc, bool diagA)
{
    f32x4 sA[4], sB[4];
#pragma unroll
    for (int n = 0; n < 4; ++n) { sA[n] = {0.f, 0.f, 0.f, 0.f}; sB[n] = {0.f, 0.f, 0.f, 0.f}; }
    __builtin_amdgcn_s_setprio(1);
#pragma unroll
    for (int n = 0; n < 4; ++n) {
        const int t  = n * 16 + fr;
        const int sw = ((t ^ (t >> 3)) & 7) << 4;
        const bf16x8 kf0 = *(const bf16x8*)((const char*)Ks + t * 128 + ((fq * 16) ^ sw));
        const bf16x8 kf1 = *(const bf16x8*)((const char*)Ks + t * 128 + ((64 + fq * 16) ^ sw));
        sA[n] = __builtin_amdgcn_mfma_f32_16x16x32_bf16(qfA[0], kf0, sA[n], 0, 0, 0);
        sA[n] = __builtin_amdgcn_mfma_f32_16x16x32_bf16(qfA[1], kf1, sA[n], 0, 0, 0);
        sB[n] = __builtin_amdgcn_mfma_f32_16x16x32_bf16(qfB[0], kf0, sB[n], 0, 0, 0);
        sB[n] = __builtin_amdgcn_mfma_f32_16x16x32_bf16(qfB[1], kf1, sB[n], 0, 0, 0);
    }
    __builtin_amdgcn_s_setprio(0);
    // A softmax -> P -> read; then B reuses the same P (same-wave DS order).
    sm_part(sA, mA, oA, olA, Pp, fr, fq, qloc, diagA);
    asm volatile("s_waitcnt lgkmcnt(0)" ::: "memory");
    __builtin_amdgcn_sched_barrier(0);
    bf16x8 pfA0, pfA1;
    PLOAD(pfA0, pfA1, Pp);
    sm_part(sB, mB, oB, olB, Pp, fr, fq, qloc, false);
    asm volatile("s_waitcnt lgkmcnt(0)" ::: "memory");
    __builtin_amdgcn_sched_barrier(0);
    bf16x8 pfB0, pfB1;
    PLOAD(pfB0, pfB1, Pp);
    __builtin_amdgcn_s_setprio(1);
#pragma unroll
    for (int nd = 0; nd < 4; ++nd) {
        const int dd = nd * 16 + fr;
        const int sw = ((dd ^ (dd >> 3)) & 7) << 4;
        const bf16x8 vf0 = *(const bf16x8*)((const char*)Vt + dd * 128 + ((fq * 16) ^ sw));
        const bf16x8 vf1 = *(const bf16x8*)((const char*)Vt + dd * 128 + ((64 + fq * 16) ^ sw));
        oA[nd] = __builtin_amdgcn_mfma_f32_16x16x32_bf16(pfA0, vf0, oA[nd], 0, 0, 0);
        oA[nd] = __builtin_amdgcn_mfma_f32_16x16x32_bf16(pfA1, vf1, oA[nd], 0, 0, 0);
        oB[nd] = __builtin_amdgcn_mfma_f32_16x16x32_bf16(pfB0, vf0, oB[nd], 0, 0, 0);
        oB[nd] = __builtin_amdgcn_mfma_f32_16x16x32_bf16(pfB1, vf1, oB[nd], 0, 0, 0);
    }
    olA = __builtin_amdgcn_mfma_f32_16x16x32_bf16(pfA0, onesf, olA, 0, 0, 0);
    olA = __builtin_amdgcn_mfma_f32_16x16x32_bf16(pfA1, onesf, olA, 0, 0, 0);
    olB = __builtin_amdgcn_mfma_f32_16x16x32_bf16(pfB0, onesf, olB, 0, 0, 0);
    olB = __builtin_amdgcn_mfma_f32_16x16x32_bf16(pfB1, onesf, olB, 0, 0, 0);
    __builtin_amdgcn_s_setprio(0);
}

__global__ __launch_bounds__(256) void attn_kernel(
    const bf16* __restrict__ qkv, const bf16* __restrict__ vt,
    bf16* __restrict__ out)
{
    const int pair = blockIdx.x;
    const int h = blockIdx.y, b = blockIdx.z;
    const int tid = threadIdx.x, wid = tid >> 6, lane = tid & 63;
    const int fr = lane & 15, fq = lane >> 4;
    const int jA = pair, jB = 31 - pair;
    const bf16* baseQ = qkv + ((long)b * T_SEQ) * 3072 + h * 64;
    const bf16* baseK = baseQ + 1024;
    const bf16* baseV = vt + (long)(h * 64) * 8192 + (long)b * T_SEQ;

    __shared__ __align__(16) bf16 Ks[2][64 * 64];    // 16384 B
    __shared__ __align__(16) bf16 Vs[2][64 * 64];    // 16384 B
    __shared__ __align__(16) bf16 Pl[4][1024];       //  8192 B -> 40960 total

    const int qrA = jA * 64 + wid * 16 + fr;
    const int qrB = jB * 64 + wid * 16 + fr;
    bf16x8 qfA[2], qfB[2];
#pragma unroll
    for (int kk = 0; kk < 2; ++kk) {
        qfA[kk] = *(const bf16x8*)(baseQ + (long)qrA * 3072 + kk * 32 + fq * 8);
        qfB[kk] = *(const bf16x8*)(baseQ + (long)qrB * 3072 + kk * 32 + fq * 8);
    }

    bf16x8 onesf;
    {
        const bf16 ov = (fr == 0) ? (bf16)1.f : (bf16)0.f;
#pragma unroll
        for (int e = 0; e < 8; ++e) onesf[e] = ov;
    }

    f32x4 oA[4], oB[4], olA, olB;
    float mA[4], mB[4];
#pragma unroll
    for (int nd = 0; nd < 4; ++nd) { oA[nd] = {0.f, 0.f, 0.f, 0.f}; oB[nd] = {0.f, 0.f, 0.f, 0.f}; }
    olA = {0.f, 0.f, 0.f, 0.f}; olB = {0.f, 0.f, 0.f, 0.f};
#pragma unroll
    for (int j = 0; j < 4; ++j) { mA[j] = -1e30f; mB[j] = -1e30f; }

    const int t_p0 = wid * 16 + (lane >> 3);
    const int t_p1 = t_p0 + 8;
    const int kcb0 = ((lane & 7) * 16) ^ (((t_p0 ^ (t_p0 >> 3)) & 7) << 4);
    const int kcb1 = ((lane & 7) * 16) ^ (((t_p1 ^ (t_p1 >> 3)) & 7) << 4);

    bf16* P = &Pl[wid][0];

    auto stage = [&](int buf, int c) {
        const long s0 = (long)c * 64;
        gload_lds16(baseK + (s0 + t_p0) * 3072 + (kcb0 >> 1), &Ks[buf][(wid * 2) * 512]);
        gload_lds16(baseK + (s0 + t_p1) * 3072 + (kcb1 >> 1), &Ks[buf][(wid * 2 + 1) * 512]);
        gload_lds16(baseV + (long)t_p0 * 8192 + s0 + (kcb0 >> 1), &Vs[buf][(wid * 2) * 512]);
        gload_lds16(baseV + (long)t_p1 * 8192 + s0 + (kcb1 >> 1), &Vs[buf][(wid * 2 + 1) * 512]);
    };

    const int nch = jB + 1;
    stage(0, 0);
    for (int c = 0; c < nch; ++c) {
        const int cur = c & 1;
        if (c + 1 < nch) { stage(cur ^ 1, c + 1); VMCNT(4); }
        else             { VMCNT(0); }
        BAR();
        if (c <= jA)
            attn_step2(Ks[cur], Vs[cur], P, qfA, qfB,
                       oA, olA, mA, oB, olB, mB, onesf, fr, fq, wid * 16, c == jA);
        else
            attn_step(Ks[cur], Vs[cur], P, qfB, oB, olB, mB, onesf,
                      fr, fq, wid * 16, c == jB);
        BAR();
    }

#pragma unroll
    for (int j = 0; j < 4; ++j) {
        const float lA = __shfl(olA[j], lane & 48, 64);
        const float lB = __shfl(olB[j], lane & 48, 64);
        const float rA = 1.f / lA, rB = 1.f / lB;
        const long rowA = (long)b * T_SEQ + jA * 64 + wid * 16 + fq * 4 + j;
        const long rowB = (long)b * T_SEQ + jB * 64 + wid * 16 + fq * 4 + j;
#pragma unroll
        for (int nd = 0; nd < 4; ++nd) {
            out[rowA * 1024 + h * 64 + nd * 16 + fr] = (bf16)(oA[nd][j] * rA);
            out[rowB * 1024 + h * 64 + nd * 16 + fr] = (bf16)(oB[nd][j] * rB);
        }
    }
}

// ---------------------------------------------------------------------------
extern "C" void kernel_launch(void* const* d_in, const int* in_sizes, int n_in,
                              void* d_out, int out_size, void* d_ws, size_t ws_size,
                              hipStream_t stream)
{
    const float* x     = (const float*)d_in[0];
    const float* Wq    = (const float*)d_in[1];
    const float* Wk    = (const float*)d_in[2];
    const float* Wv    = (const float*)d_in[3];
    const float* Wproj = (const float*)d_in[4];
    const float* bproj = (const float*)d_in[5];
    const float* W1    = (const float*)d_in[6];
    const float* b1    = (const float*)d_in[7];
    const float* W2    = (const float*)d_in[8];
    const float* b2    = (const float*)d_in[9];
    const float* W3    = (const float*)d_in[10];
    const float* b3    = (const float*)d_in[11];
    const float* ln1g  = (const float*)d_in[12];
    const float* ln1b  = (const float*)d_in[13];
    const float* ln2g  = (const float*)d_in[14];
    const float* ln2b  = (const float*)d_in[15];

    char* ws = (char*)d_ws;
    size_t off = 0;
    auto alloc = [&](size_t bytes) {
        void* p = ws + off;
        off += (bytes + 255) & ~(size_t)255;
        return p;
    };
    bf16* Wqkv_t  = (bf16*)alloc(3072ul * 1024 * 2);
    bf16* Wproj_t = (bf16*)alloc(1024ul * 1024 * 2);
    bf16* W1_t    = (bf16*)alloc(4096ul * 1024 * 2);
    bf16* W2_t    = (bf16*)alloc(4096ul * 4096 * 2);
    bf16* W3_t    = (bf16*)alloc(1024ul * 4096 * 2);
    bf16* hbuf    = (bf16*)alloc(8192ul * 1024 * 2);
    bf16* x1b     = (bf16*)alloc(8192ul * 1024 * 2);   // bf16 residual stream
    bf16* a1      = (bf16*)alloc(8192ul * 4096 * 2);   // also hosts vt pre-FF1
    char* R1      = (char*)alloc(8192ul * 4096 * 2);
    bf16* qkvb    = (bf16*)R1;
    bf16* attnb   = (bf16*)(R1 + 8192ul * 3072 * 2);
    bf16* a2      = (bf16*)R1;
    bf16* vt      = a1;   // [1024][8192] V^T; dead once FF1 writes a1

    hipFuncSetAttribute(reinterpret_cast<const void*>(&gemm256<1>),
                        hipFuncAttributeMaxDynamicSharedMemorySize, 131072);
    hipFuncSetAttribute(reinterpret_cast<const void*>(&gemm256n<0>),
                        hipFuncAttributeMaxDynamicSharedMemorySize, 98304);
    hipFuncSetAttribute(reinterpret_cast<const void*>(&gemm256n<3>),
                        hipFuncAttributeMaxDynamicSharedMemorySize, 98304);
    hipFuncSetAttribute(reinterpret_cast<const void*>(&gemm256n<4>),
                        hipFuncAttributeMaxDynamicSharedMemorySize, 98304);

    const dim3 tb(32, 8);
    transpose_f32_bf16<<<dim3(2, 32, 16), tb, 0, stream>>>(Wq, Wqkv_t,                1024, 64, 1024);
    transpose_f32_bf16<<<dim3(2, 32, 16), tb, 0, stream>>>(Wk, Wqkv_t + 1024l * 1024, 1024, 64, 1024);
    transpose_f32_bf16<<<dim3(2, 32, 16), tb, 0, stream>>>(Wv, Wqkv_t + 2048l * 1024, 1024, 64, 1024);
    transpose_f32_bf16<<<dim3(32, 32, 1),   tb, 0, stream>>>(Wproj, Wproj_t, 1024, 1024, 1024);
    transpose_f32_bf16<<<dim3(128, 32, 1),  tb, 0, stream>>>(W1, W1_t, 1024, 4096, 1024);
    transpose_f32_bf16<<<dim3(128, 128, 1), tb, 0, stream>>>(W2, W2_t, 4096, 4096, 4096);
    transpose_f32_bf16<<<dim3(32, 128, 1),  tb, 0, stream>>>(W3, W3_t, 4096, 1024, 4096);

    ln_kernel<<<8192, 256, 0, stream>>>(x, ln1g, ln1b, hbuf);
    // QKV: 32 x 24 = 768 blocks
    gemm256n<0><<<768, 512, 98304, stream>>>(hbuf, Wqkv_t, nullptr, nullptr, qkvb,
                                             8192, 3072, 1024, 24);
    // V^T: qkvb cols [2048,3072) -> vt [1024][8192]
    transpose_bf16<<<dim3(32, 256), tb, 0, stream>>>(qkvb + 2048, vt, 3072, 8192);
    // attention: paired tiles, 1024 blocks; 40960 B LDS -> 4 blocks/CU target
    attn_kernel<<<dim3(16, 16, 4), 256, 0, stream>>>(qkvb, vt, attnb);
    // proj: bias + fp32 resid(x) -> bf16 x1b
    gemm256n<3><<<256, 512, 98304, stream>>>(attnb, Wproj_t, bproj, x, x1b,
                                             8192, 1024, 1024, 8);
    ln_kernel_b<<<8192, 256, 0, stream>>>(x1b, ln2g, ln2b, hbuf);
    // FF1: 512 blocks
    gemm256<1><<<512, 512, 131072, stream>>>(hbuf, W1_t, b1, nullptr, a1,
                                             8192, 4096, 1024, 16);
    // FF2: 512 blocks
    gemm256<1><<<512, 512, 131072, stream>>>(a1, W2_t, b2, nullptr, a2,
                                             8192, 4096, 4096, 16);
    // FF3: bias + bf16 resid(x1b) -> fp32 d_out
    gemm256n<4><<<256, 512, 98304, stream>>>(a2, W3_t, b3, x1b, (float*)d_out,
                                             8192, 1024, 4096, 8);
}

// Round 15
// 665.060 us; speedup vs baseline: 1.1661x; 1.1661x over previous
//
#include <hip/hip_runtime.h>

typedef __bf16 bf16;
typedef bf16  bf16x8 __attribute__((ext_vector_type(8)));
typedef bf16  bf16x4 __attribute__((ext_vector_type(4)));
typedef float f32x4  __attribute__((ext_vector_type(4)));

#define T_SEQ 2048

__device__ __forceinline__ void gload_lds16(const bf16* g, bf16* l) {
    __builtin_amdgcn_global_load_lds(
        (const __attribute__((address_space(1))) unsigned int*)g,
        (__attribute__((address_space(3))) unsigned int*)l,
        16, 0, 0);
}

#define VMCNT(n) asm volatile("s_waitcnt vmcnt(" #n ")" ::: "memory")
#define BAR() do { asm volatile("" ::: "memory"); __builtin_amdgcn_s_barrier(); \
                   asm volatile("" ::: "memory"); } while (0)

// ---------------------------------------------------------------------------
// Tiled transpose fp32 [R][Cc] -> bf16 [Cc][R], batched on z.
// ---------------------------------------------------------------------------
__global__ __launch_bounds__(256) void transpose_f32_bf16(
    const float* __restrict__ in, bf16* __restrict__ out, int R, int Cc, int ldo)
{
    __shared__ float tile[32][33];
    const int bx = blockIdx.x * 32;
    const int by = blockIdx.y * 32;
    const long bi = (long)blockIdx.z * R * Cc;
    const long bo = (long)blockIdx.z * Cc * ldo;
    const int tx = threadIdx.x, ty = threadIdx.y;
#pragma unroll
    for (int i = 0; i < 4; ++i)
        tile[ty + i * 8][tx] = in[bi + (long)(by + ty + i * 8) * Cc + bx + tx];
    __syncthreads();
#pragma unroll
    for (int i = 0; i < 4; ++i)
        out[bo + (long)(bx + ty + i * 8) * ldo + by + tx] = (bf16)tile[tx][ty + i * 8];
}

// ---------------------------------------------------------------------------
// Tiled transpose bf16 [rows][ldi] -> bf16 [cols][ldo] (for V^T).
// ---------------------------------------------------------------------------
__global__ __launch_bounds__(256) void transpose_bf16(
    const bf16* __restrict__ in, bf16* __restrict__ out, int ldi, int ldo)
{
    __shared__ bf16 tile[32][33];
    const int bx = blockIdx.x * 32;
    const int by = blockIdx.y * 32;
    const int tx = threadIdx.x, ty = threadIdx.y;
#pragma unroll
    for (int i = 0; i < 4; ++i)
        tile[ty + i * 8][tx] = in[(long)(by + ty + i * 8) * ldi + bx + tx];
    __syncthreads();
#pragma unroll
    for (int i = 0; i < 4; ++i)
        out[(long)(bx + ty + i * 8) * ldo + by + tx] = tile[tx][ty + i * 8];
}

// ---------------------------------------------------------------------------
// LayerNorm fp32 input -> bf16; and bf16-input variant.
// ---------------------------------------------------------------------------
__global__ __launch_bounds__(256) void ln_kernel(
    const float* __restrict__ x, const float* __restrict__ g,
    const float* __restrict__ bb, bf16* __restrict__ out)
{
    const long row = blockIdx.x;
    const int tid = threadIdx.x;
    const float4 v = ((const float4*)(x + row * 1024))[tid];
    float s  = v.x + v.y + v.z + v.w;
    float s2 = v.x * v.x + v.y * v.y + v.z * v.z + v.w * v.w;
#pragma unroll
    for (int off = 32; off >= 1; off >>= 1) {
        s  += __shfl_xor(s,  off, 64);
        s2 += __shfl_xor(s2, off, 64);
    }
    __shared__ float red[8];
    const int wid = tid >> 6;
    if ((tid & 63) == 0) { red[wid] = s; red[4 + wid] = s2; }
    __syncthreads();
    s  = red[0] + red[1] + red[2] + red[3];
    s2 = red[4] + red[5] + red[6] + red[7];
    const float mu   = s * (1.f / 1024.f);
    const float rstd = rsqrtf(s2 * (1.f / 1024.f) - mu * mu + 1e-5f);
    const float4 gv = ((const float4*)g)[tid];
    const float4 bv = ((const float4*)bb)[tid];
    bf16x4 ov;
    ov[0] = (bf16)((v.x - mu) * rstd * gv.x + bv.x);
    ov[1] = (bf16)((v.y - mu) * rstd * gv.y + bv.y);
    ov[2] = (bf16)((v.z - mu) * rstd * gv.z + bv.z);
    ov[3] = (bf16)((v.w - mu) * rstd * gv.w + bv.w);
    *(bf16x4*)(out + row * 1024 + tid * 4) = ov;
}

__global__ __launch_bounds__(256) void ln_kernel_b(
    const bf16* __restrict__ x, const float* __restrict__ g,
    const float* __restrict__ bb, bf16* __restrict__ out)
{
    const long row = blockIdx.x;
    const int tid = threadIdx.x;
    const bf16x4 vb = ((const bf16x4*)(x + row * 1024))[tid];
    const float v0 = (float)vb[0], v1 = (float)vb[1];
    const float v2 = (float)vb[2], v3 = (float)vb[3];
    float s  = v0 + v1 + v2 + v3;
    float s2 = v0 * v0 + v1 * v1 + v2 * v2 + v3 * v3;
#pragma unroll
    for (int off = 32; off >= 1; off >>= 1) {
        s  += __shfl_xor(s,  off, 64);
        s2 += __shfl_xor(s2, off, 64);
    }
    __shared__ float red[8];
    const int wid = tid >> 6;
    if ((tid & 63) == 0) { red[wid] = s; red[4 + wid] = s2; }
    __syncthreads();
    s  = red[0] + red[1] + red[2] + red[3];
    s2 = red[4] + red[5] + red[6] + red[7];
    const float mu   = s * (1.f / 1024.f);
    const float rstd = rsqrtf(s2 * (1.f / 1024.f) - mu * mu + 1e-5f);
    const float4 gv = ((const float4*)g)[tid];
    const float4 bv = ((const float4*)bb)[tid];
    bf16x4 ov;
    ov[0] = (bf16)((v0 - mu) * rstd * gv.x + bv.x);
    ov[1] = (bf16)((v1 - mu) * rstd * gv.y + bv.y);
    ov[2] = (bf16)((v2 - mu) * rstd * gv.z + bv.z);
    ov[3] = (bf16)((v3 - mu) * rstd * gv.w + bv.w);
    *(bf16x4*)(out + row * 1024 + tid * 4) = ov;
}

// ---------------------------------------------------------------------------
// Shared fragment-load / MFMA macros for the 256-row GEMMs.
// ---------------------------------------------------------------------------
#define LOADA(BUFP, QM) do {                                                   \
    const char* ab_ = (BUFP) + (size_t)((wr * 64 + (QM) * 128 + fr) * 128);    \
    _Pragma("unroll") for (int m_ = 0; m_ < 4; ++m_) {                         \
        af[m_][0] = *(const bf16x8*)(ab_ + m_ * 2048 + so0);                   \
        af[m_][1] = *(const bf16x8*)(ab_ + m_ * 2048 + so1); } } while (0)

#define LOADB(BUFP, QN, DST) do {                                              \
    const char* bb_ = (BUFP) + (size_t)((wc * 32 + (QN) * 128 + fr) * 128);    \
    _Pragma("unroll") for (int n_ = 0; n_ < 2; ++n_) {                         \
        DST[n_][0] = *(const bf16x8*)(bb_ + n_ * 2048 + so0);                  \
        DST[n_][1] = *(const bf16x8*)(bb_ + n_ * 2048 + so1); } } while (0)

#define MMA(ACC, BSET) do { __builtin_amdgcn_s_setprio(1);                     \
    _Pragma("unroll") for (int m_ = 0; m_ < 4; ++m_)                           \
    _Pragma("unroll") for (int n_ = 0; n_ < 2; ++n_) {                         \
        ACC[m_][n_] = __builtin_amdgcn_mfma_f32_16x16x32_bf16(                 \
            af[m_][0], BSET[n_][0], ACC[m_][n_], 0, 0, 0);                     \
        ACC[m_][n_] = __builtin_amdgcn_mfma_f32_16x16x32_bf16(                 \
            af[m_][1], BSET[n_][1], ACC[m_][n_], 0, 0, 0); }                   \
    __builtin_amdgcn_s_setprio(0); } while (0)

// ---------------------------------------------------------------------------
// 256x256 bf16 GEMM (round-8/9 proven): 1.5-tile-ahead pipeline + B0
// fragment register retention (ph3 has no ds_reads).
// ---------------------------------------------------------------------------
#define TB_DEEP(W1N, W3N, ISSN, ISSC) do {                                     \
    const char* abuf = cAs + ((size_t)cur << 15);                              \
    const char* bbuf = cBs + ((size_t)cur << 15);                              \
    const long kb  = (long)(k + 1) * 64;                                       \
    const long kb2 = (long)(k + 2) * 64;                                       \
    LOADA(abuf, 0);                                                            \
    LOADB(bbuf, 0, bfv0);                                                      \
    if (ISSN) stageB(nxt, 0, kb);        /* B0[k+1] */                         \
    BAR(); MMA(a00, bfv0); BAR();                                              \
    LOADB(bbuf, 1, bfv1);                                                      \
    if (ISSN) stageA(nxt, 1, kb);        /* A1[k+1] */                         \
    VMCNT(W1N);                                                                \
    BAR(); MMA(a01, bfv1); BAR();                                              \
    LOADA(abuf, 1);                                                            \
    if (ISSC) stageA(cur, 0, kb2);       /* A0[k+2] */                         \
    BAR(); MMA(a11, bfv1); BAR();                                              \
    if (ISSC) stageB(cur, 1, kb2);       /* B1[k+2] */                         \
    VMCNT(W3N);                                                                \
    BAR(); MMA(a10, bfv0); BAR(); } while (0)

template <int MODE>
__global__ __launch_bounds__(512, 1) void gemm256(
    const bf16* __restrict__ A, const bf16* __restrict__ Bt,
    const float* __restrict__ bias, const float* __restrict__ resid,
    void* __restrict__ outp, int M, int N, int K, int nbn)
{
    extern __shared__ __align__(16) char smem[];
    char* cAs = smem;
    char* cBs = smem + 65536;

    const int tid = threadIdx.x;
    const int wid = tid >> 6, lane = tid & 63;
    const int wr = wid >> 2, wc = wid & 3;
    const int fr = lane & 15, fq = lane >> 4;

    const int nwg = gridDim.x;
    const int cpx = nwg >> 3;
    const int b0  = blockIdx.x;
    const int bid = (b0 & 7) * cpx + (b0 >> 3);
    const long bm = bid / nbn, bn = bid % nbn;
    const long bmrow = bm * 256, bnrow = bn * 256;

    const int srow0 = wid * 8 + (lane >> 3);
    const int sslot = (lane & 7) ^ (lane >> 3);
    auto stageA = [&](int buf, int h, long kt) {
        const bf16* g = A + (size_t)(bmrow + h * 128 + srow0) * K + kt + sslot * 8;
        char* l = cAs + ((size_t)buf << 15) + h * 16384 + (size_t)wid * 1024;
        gload_lds16(g, (bf16*)l);
        gload_lds16(g + (size_t)64 * K, (bf16*)(l + 8192));
    };
    auto stageB = [&](int buf, int h, long kt) {
        const bf16* g = Bt + (size_t)(bnrow + h * 128 + srow0) * K + kt + sslot * 8;
        char* l = cBs + ((size_t)buf << 15) + h * 16384 + (size_t)wid * 1024;
        gload_lds16(g, (bf16*)l);
        gload_lds16(g + (size_t)64 * K, (bf16*)(l + 8192));
    };

    const int sx  = fr & 7;
    const int so0 = ((fq) ^ sx) * 16;
    const int so1 = ((4 + fq) ^ sx) * 16;

    bf16x8 af[4][2], bfv0[2][2], bfv1[2][2];
    f32x4 a00[4][2], a01[4][2], a11[4][2], a10[4][2];
#pragma unroll
    for (int m = 0; m < 4; ++m)
#pragma unroll
        for (int n = 0; n < 2; ++n) {
            a00[m][n] = {0.f, 0.f, 0.f, 0.f}; a01[m][n] = {0.f, 0.f, 0.f, 0.f};
            a11[m][n] = {0.f, 0.f, 0.f, 0.f}; a10[m][n] = {0.f, 0.f, 0.f, 0.f};
        }

    stageA(0, 0, 0);      // A0_0
    stageB(0, 1, 0);      // B1_0
    stageB(0, 0, 0);      // B0_0
    stageA(0, 1, 0);      // A1_0
    stageA(1, 0, 64);     // A0_1
    stageB(1, 1, 64);     // B1_1
    VMCNT(6);
    BAR();

    const int NT = K >> 6;
    int cur, nxt;
    int k = 0;
    for (; k < NT - 2; ++k) {
        cur = k & 1; nxt = cur ^ 1;
        TB_DEEP(8, 6, true, true);
    }
    cur = k & 1; nxt = cur ^ 1;
    TB_DEEP(8, 2, true, false);          // k = NT-2
    ++k;
    cur = k & 1; nxt = cur ^ 1;
    TB_DEEP(0, 0, false, false);         // k = NT-1

    auto writeQ = [&](f32x4 (&acc)[4][2], int QM, int QN) {
#pragma unroll
        for (int m = 0; m < 4; ++m) {
            const long row0 = bmrow + wr * 64 + QM * 128 + m * 16 + fq * 4;
#pragma unroll
            for (int n = 0; n < 2; ++n) {
                const long col = bnrow + wc * 32 + QN * 128 + n * 16 + fr;
                const float bv = (MODE == 0) ? 0.f : bias[col];
#pragma unroll
                for (int j = 0; j < 4; ++j) {
                    const long row = row0 + j;
                    float v = acc[m][n][j] + bv;
                    if (MODE == 1) v = fmaxf(v, 0.f);
                    if (MODE == 2) {
                        v += resid[row * N + col];
                        ((float*)outp)[row * N + col] = v;
                    } else {
                        ((bf16*)outp)[row * N + col] = (bf16)v;
                    }
                }
            }
        }
    };
    writeQ(a00, 0, 0); writeQ(a01, 0, 1); writeQ(a11, 1, 1); writeQ(a10, 1, 0);
}

// ---------------------------------------------------------------------------
// 256x128 bf16 GEMM (PROVEN schedule). MODE: 0 plain->bf16;
// 3 bias+f32resid->bf16; 4 bias+bf16resid->f32.
// ---------------------------------------------------------------------------
#define TILE_BODY_N(PRE, LAST) do {                                            \
    const char* abuf = cAs + ((size_t)cur << 15);                              \
    const char* bbuf = cBs + ((size_t)cur << 14);                              \
    const long kn = (long)(k + 1) * 64;                                        \
    LOADA(abuf, 0);                                                            \
    LOADB(bbuf, 0, bfv);                                                       \
    if (PRE) { stageA(nxt, 0, kn); stageB(nxt, kn); stageA(nxt, 1, kn);        \
               VMCNT(6); }                                                     \
    else     { VMCNT(0); }                                                     \
    BAR(); MMA(aq0, bfv); BAR();                                               \
    LOADA(abuf, 1);                                                            \
    if (PRE) { VMCNT(2); }                                                     \
    if (!LAST) { BAR(); }                                                      \
    MMA(aq1, bfv);                                                             \
    if (!LAST) { BAR(); } } while (0)

template <int MODE>
__global__ __launch_bounds__(512, 2) void gemm256n(
    const bf16* __restrict__ A, const bf16* __restrict__ Bt,
    const float* __restrict__ bias, const void* __restrict__ resid,
    void* __restrict__ outp, int M, int N, int K, int nbn)
{
    extern __shared__ __align__(16) char smem[];
    char* cAs = smem;            // 2 x 32 KiB
    char* cBs = smem + 65536;    // 2 x 16 KiB

    const int tid = threadIdx.x;
    const int wid = tid >> 6, lane = tid & 63;
    const int wr = wid >> 2, wc = wid & 3;
    const int fr = lane & 15, fq = lane >> 4;

    const int nwg = gridDim.x;
    const int cpx = nwg >> 3;
    const int b0  = blockIdx.x;
    const int bid = (b0 & 7) * cpx + (b0 >> 3);
    const long bm = bid / nbn, bn = bid % nbn;
    const long bmrow = bm * 256, bnrow = bn * 128;

    const int srow0 = wid * 8 + (lane >> 3);
    const int sslot = (lane & 7) ^ (lane >> 3);
    auto stageA = [&](int buf, int h, long kt) {
        const bf16* g = A + (size_t)(bmrow + h * 128 + srow0) * K + kt + sslot * 8;
        char* l = cAs + ((size_t)buf << 15) + h * 16384 + (size_t)wid * 1024;
        gload_lds16(g, (bf16*)l);
        gload_lds16(g + (size_t)64 * K, (bf16*)(l + 8192));
    };
    auto stageB = [&](int buf, long kt) {
        const bf16* g = Bt + (size_t)(bnrow + srow0) * K + kt + sslot * 8;
        char* l = cBs + ((size_t)buf << 14) + (size_t)wid * 1024;
        gload_lds16(g, (bf16*)l);
        gload_lds16(g + (size_t)64 * K, (bf16*)(l + 8192));
    };

    const int sx  = fr & 7;
    const int so0 = ((fq) ^ sx) * 16;
    const int so1 = ((4 + fq) ^ sx) * 16;

    bf16x8 af[4][2], bfv[2][2];
    f32x4 aq0[4][2], aq1[4][2];
#pragma unroll
    for (int m = 0; m < 4; ++m)
#pragma unroll
        for (int n = 0; n < 2; ++n) {
            aq0[m][n] = {0.f, 0.f, 0.f, 0.f};
            aq1[m][n] = {0.f, 0.f, 0.f, 0.f};
        }

    stageA(0, 0, 0); stageB(0, 0); stageA(0, 1, 0);
    VMCNT(2);
    BAR();

    const int NT = K >> 6;
    int cur = 0, nxt = 1;
    int k = 0;
    for (; k < NT - 1; ++k) {
        cur = k & 1; nxt = cur ^ 1;
        TILE_BODY_N(true, false);
    }
    cur = k & 1; nxt = cur ^ 1;
    TILE_BODY_N(false, true);

    auto writeQ = [&](f32x4 (&acc)[4][2], int QM) {
#pragma unroll
        for (int m = 0; m < 4; ++m) {
            const long row0 = bmrow + wr * 64 + QM * 128 + m * 16 + fq * 4;
#pragma unroll
            for (int n = 0; n < 2; ++n) {
                const long col = bnrow + wc * 32 + n * 16 + fr;
                const float bv = (MODE == 0) ? 0.f : bias[col];
#pragma unroll
                for (int j = 0; j < 4; ++j) {
                    const long row = row0 + j;
                    float v = acc[m][n][j] + bv;
                    if (MODE == 3) {
                        v += ((const float*)resid)[row * N + col];
                        ((bf16*)outp)[row * N + col] = (bf16)v;
                    } else if (MODE == 4) {
                        v += (float)((const bf16*)resid)[row * N + col];
                        ((float*)outp)[row * N + col] = v;
                    } else {
                        ((bf16*)outp)[row * N + col] = (bf16)v;
                    }
                }
            }
        }
    };
    writeQ(aq0, 0); writeQ(aq1, 1);
}

// ---------------------------------------------------------------------------
// Flash attention (round-9 PROVEN, measured best): paired q-tiles, fused A+B
// steps, TWO padded P[16][72] buffers (stride 144 B = conflict-clean),
// glds-staged K/V double-buffer with counted VMCNT(4), ones-column l,
// defer-max.
// ---------------------------------------------------------------------------
__device__ __forceinline__ void sm_part(
    f32x4* s, float* mj, f32x4* o, f32x4& o_l, bf16* Pp,
    int fr, int fq, int qloc, bool diag)
{
    float v[4][4], mxj[4];
#pragma unroll
    for (int j = 0; j < 4; ++j) {
        const int qg = qloc + fq * 4 + j;
        v[0][j] = s[0][j] * 0.03125f;
        v[1][j] = s[1][j] * 0.03125f;
        v[2][j] = s[2][j] * 0.03125f;
        v[3][j] = s[3][j] * 0.03125f;
        if (diag) {
            if (fr      > qg) v[0][j] = -1e30f;
            if (16 + fr > qg) v[1][j] = -1e30f;
            if (32 + fr > qg) v[2][j] = -1e30f;
            if (48 + fr > qg) v[3][j] = -1e30f;
        }
        float mx = fmaxf(fmaxf(v[0][j], v[1][j]), fmaxf(v[2][j], v[3][j]));
#pragma unroll
        for (int off = 1; off <= 8; off <<= 1) mx = fmaxf(mx, __shfl_xor(mx, off, 16));
        mxj[j] = mx;
    }
    float need = fmaxf(fmaxf(mxj[0] - mj[0], mxj[1] - mj[1]),
                       fmaxf(mxj[2] - mj[2], mxj[3] - mj[3]));
    if (__any(need > 8.f)) {
#pragma unroll
        for (int j = 0; j < 4; ++j) {
            const float mn   = fmaxf(mj[j], mxj[j]);
            const float corr = __expf(mj[j] - mn);
            mj[j] = mn;
#pragma unroll
            for (int nd = 0; nd < 4; ++nd) o[nd][j] *= corr;
            o_l[j] *= corr;
        }
    }
#pragma unroll
    for (int j = 0; j < 4; ++j) {
        bf16* prow = Pp + (fq * 4 + j) * 72;
        prow[fr]      = (bf16)__expf(v[0][j] - mj[j]);
        prow[16 + fr] = (bf16)__expf(v[1][j] - mj[j]);
        prow[32 + fr] = (bf16)__expf(v[2][j] - mj[j]);
        prow[48 + fr] = (bf16)__expf(v[3][j] - mj[j]);
    }
}

__device__ __forceinline__ void attn_step(
    const bf16* __restrict__ Ks, const bf16* __restrict__ Vt,
    bf16* __restrict__ Pp, const bf16x8* qf,
    f32x4* o, f32x4& o_l, float* mj, const bf16x8 onesf,
    int fr, int fq, int qloc, bool diag)
{
    f32x4 s[4];
#pragma unroll
    for (int n = 0; n < 4; ++n) s[n] = {0.f, 0.f, 0.f, 0.f};
    __builtin_amdgcn_s_setprio(1);
#pragma unroll
    for (int n = 0; n < 4; ++n) {
        const int t  = n * 16 + fr;
        const int sw = ((t ^ (t >> 3)) & 7) << 4;
        const bf16x8 kf0 = *(const bf16x8*)((const char*)Ks + t * 128 + ((fq * 16) ^ sw));
        const bf16x8 kf1 = *(const bf16x8*)((const char*)Ks + t * 128 + ((64 + fq * 16) ^ sw));
        s[n] = __builtin_amdgcn_mfma_f32_16x16x32_bf16(qf[0], kf0, s[n], 0, 0, 0);
        s[n] = __builtin_amdgcn_mfma_f32_16x16x32_bf16(qf[1], kf1, s[n], 0, 0, 0);
    }
    __builtin_amdgcn_s_setprio(0);
    sm_part(s, mj, o, o_l, Pp, fr, fq, qloc, diag);
    asm volatile("s_waitcnt lgkmcnt(0)" ::: "memory");
    __builtin_amdgcn_sched_barrier(0);
    const bf16x8 pf0 = *(const bf16x8*)(Pp + fr * 72 + fq * 8);
    const bf16x8 pf1 = *(const bf16x8*)(Pp + fr * 72 + 32 + fq * 8);
    __builtin_amdgcn_s_setprio(1);
#pragma unroll
    for (int nd = 0; nd < 4; ++nd) {
        const int dd = nd * 16 + fr;
        const int sw = ((dd ^ (dd >> 3)) & 7) << 4;
        const bf16x8 vf0 = *(const bf16x8*)((const char*)Vt + dd * 128 + ((fq * 16) ^ sw));
        const bf16x8 vf1 = *(const bf16x8*)((const char*)Vt + dd * 128 + ((64 + fq * 16) ^ sw));
        o[nd] = __builtin_amdgcn_mfma_f32_16x16x32_bf16(pf0, vf0, o[nd], 0, 0, 0);
        o[nd] = __builtin_amdgcn_mfma_f32_16x16x32_bf16(pf1, vf1, o[nd], 0, 0, 0);
    }
    o_l = __builtin_amdgcn_mfma_f32_16x16x32_bf16(pf0, onesf, o_l, 0, 0, 0);
    o_l = __builtin_amdgcn_mfma_f32_16x16x32_bf16(pf1, onesf, o_l, 0, 0, 0);
    __builtin_amdgcn_s_setprio(0);
}

__device__ __forceinline__ void attn_step2(
    const bf16* __restrict__ Ks, const bf16* __restrict__ Vt,
    bf16* __restrict__ PpA, bf16* __restrict__ PpB,
    const bf16x8* qfA, const bf16x8* qfB,
    f32x4* oA, f32x4& olA, float* mA,
    f32x4* oB, f32x4& olB, float* mB,
    const bf16x8 onesf, int fr, int fq, int qloc, bool diagA)
{
    f32x4 sA[4], sB[4];
#pragma unroll
    for (int n = 0; n < 4; ++n) { sA[n] = {0.f, 0.f, 0.f, 0.f}; sB[n] = {0.f, 0.f, 0.f, 0.f}; }
    __builtin_amdgcn_s_setprio(1);
#pragma unroll
    for (int n = 0; n < 4; ++n) {
        const int t  = n * 16 + fr;
        const int sw = ((t ^ (t >> 3)) & 7) << 4;
        const bf16x8 kf0 = *(const bf16x8*)((const char*)Ks + t * 128 + ((fq * 16) ^ sw));
        const bf16x8 kf1 = *(const bf16x8*)((const char*)Ks + t * 128 + ((64 + fq * 16) ^ sw));
        sA[n] = __builtin_amdgcn_mfma_f32_16x16x32_bf16(qfA[0], kf0, sA[n], 0, 0, 0);
        sA[n] = __builtin_amdgcn_mfma_f32_16x16x32_bf16(qfA[1], kf1, sA[n], 0, 0, 0);
        sB[n] = __builtin_amdgcn_mfma_f32_16x16x32_bf16(qfB[0], kf0, sB[n], 0, 0, 0);
        sB[n] = __builtin_amdgcn_mfma_f32_16x16x32_bf16(qfB[1], kf1, sB[n], 0, 0, 0);
    }
    __builtin_amdgcn_s_setprio(0);
    sm_part(sA, mA, oA, olA, PpA, fr, fq, qloc, diagA);
    sm_part(sB, mB, oB, olB, PpB, fr, fq, qloc, false);
    asm volatile("s_waitcnt lgkmcnt(0)" ::: "memory");
    __builtin_amdgcn_sched_barrier(0);
    const bf16x8 pfA0 = *(const bf16x8*)(PpA + fr * 72 + fq * 8);
    const bf16x8 pfA1 = *(const bf16x8*)(PpA + fr * 72 + 32 + fq * 8);
    const bf16x8 pfB0 = *(const bf16x8*)(PpB + fr * 72 + fq * 8);
    const bf16x8 pfB1 = *(const bf16x8*)(PpB + fr * 72 + 32 + fq * 8);
    __builtin_amdgcn_s_setprio(1);
#pragma unroll
    for (int nd = 0; nd < 4; ++nd) {
        const int dd = nd * 16 + fr;
        const int sw = ((dd ^ (dd >> 3)) & 7) << 4;
        const bf16x8 vf0 = *(const bf16x8*)((const char*)Vt + dd * 128 + ((fq * 16) ^ sw));
        const bf16x8 vf1 = *(const bf16x8*)((const char*)Vt + dd * 128 + ((64 + fq * 16) ^ sw));
        oA[nd] = __builtin_amdgcn_mfma_f32_16x16x32_bf16(pfA0, vf0, oA[nd], 0, 0, 0);
        oA[nd] = __builtin_amdgcn_mfma_f32_16x16x32_bf16(pfA1, vf1, oA[nd], 0, 0, 0);
        oB[nd] = __builtin_amdgcn_mfma_f32_16x16x32_bf16(pfB0, vf0, oB[nd], 0, 0, 0);
        oB[nd] = __builtin_amdgcn_mfma_f32_16x16x32_bf16(pfB1, vf1, oB[nd], 0, 0, 0);
    }
    olA = __builtin_amdgcn_mfma_f32_16x16x32_bf16(pfA0, onesf, olA, 0, 0, 0);
    olA = __builtin_amdgcn_mfma_f32_16x16x32_bf16(pfA1, onesf, olA, 0, 0, 0);
    olB = __builtin_amdgcn_mfma_f32_16x16x32_bf16(pfB0, onesf, olB, 0, 0, 0);
    olB = __builtin_amdgcn_mfma_f32_16x16x32_bf16(pfB1, onesf, olB, 0, 0, 0);
    __builtin_amdgcn_s_setprio(0);
}

__global__ __launch_bounds__(256) void attn_kernel(
    const bf16* __restrict__ qkv, const bf16* __restrict__ vt,
    bf16* __restrict__ out)
{
    const int pair = blockIdx.x;
    const int h = blockIdx.y, b = blockIdx.z;
    const int tid = threadIdx.x, wid = tid >> 6, lane = tid & 63;
    const int fr = lane & 15, fq = lane >> 4;
    const int jA = pair, jB = 31 - pair;
    const bf16* baseQ = qkv + ((long)b * T_SEQ) * 3072 + h * 64;
    const bf16* baseK = baseQ + 1024;
    const bf16* baseV = vt + (long)(h * 64) * 8192 + (long)b * T_SEQ;

    __shared__ __align__(16) bf16 Ks[2][64 * 64];
    __shared__ __align__(16) bf16 Vs[2][64 * 64];
    __shared__ __align__(16) bf16 Plds[2][4][16 * 72];

    const int qrA = jA * 64 + wid * 16 + fr;
    const int qrB = jB * 64 + wid * 16 + fr;
    bf16x8 qfA[2], qfB[2];
#pragma unroll
    for (int kk = 0; kk < 2; ++kk) {
        qfA[kk] = *(const bf16x8*)(baseQ + (long)qrA * 3072 + kk * 32 + fq * 8);
        qfB[kk] = *(const bf16x8*)(baseQ + (long)qrB * 3072 + kk * 32 + fq * 8);
    }

    bf16x8 onesf;
    {
        const bf16 ov = (fr == 0) ? (bf16)1.f : (bf16)0.f;
#pragma unroll
        for (int e = 0; e < 8; ++e) onesf[e] = ov;
    }

    f32x4 oA[4], oB[4], olA, olB;
    float mA[4], mB[4];
#pragma unroll
    for (int nd = 0; nd < 4; ++nd) { oA[nd] = {0.f, 0.f, 0.f, 0.f}; oB[nd] = {0.f, 0.f, 0.f, 0.f}; }
    olA = {0.f, 0.f, 0.f, 0.f}; olB = {0.f, 0.f, 0.f, 0.f};
#pragma unroll
    for (int j = 0; j < 4; ++j) { mA[j] = -1e30f; mB[j] = -1e30f; }

    const int t_p0 = wid * 16 + (lane >> 3);
    const int t_p1 = t_p0 + 8;
    const int kcb0 = ((lane & 7) * 16) ^ (((t_p0 ^ (t_p0 >> 3)) & 7) << 4);
    const int kcb1 = ((lane & 7) * 16) ^ (((t_p1 ^ (t_p1 >> 3)) & 7) << 4);

    bf16* PA = &Plds[0][wid][0];
    bf16* PB = &Plds[1][wid][0];

    auto stage = [&](int buf, int c) {
        const long s0 = (long)c * 64;
        gload_lds16(baseK + (s0 + t_p0) * 3072 + (kcb0 >> 1), &Ks[buf][(wid * 2) * 512]);
        gload_lds16(baseK + (s0 + t_p1) * 3072 + (kcb1 >> 1), &Ks[buf][(wid * 2 + 1) * 512]);
        gload_lds16(baseV + (long)t_p0 * 8192 + s0 + (kcb0 >> 1), &Vs[buf][(wid * 2) * 512]);
        gload_lds16(baseV + (long)t_p1 * 8192 + s0 + (kcb1 >> 1), &Vs[buf][(wid * 2 + 1) * 512]);
    };

    const int nch = jB + 1;
    stage(0, 0);
    for (int c = 0; c < nch; ++c) {
        const int cur = c & 1;
        if (c + 1 < nch) { stage(cur ^ 1, c + 1); VMCNT(4); }
        else             { VMCNT(0); }
        BAR();
        if (c <= jA)
            attn_step2(Ks[cur], Vs[cur], PA, PB, qfA, qfB,
                       oA, olA, mA, oB, olB, mB, onesf, fr, fq, wid * 16, c == jA);
        else
            attn_step(Ks[cur], Vs[cur], PB, qfB, oB, olB, mB, onesf,
                      fr, fq, wid * 16, c == jB);
        BAR();
    }

#pragma unroll
    for (int j = 0; j < 4; ++j) {
        const float lA = __shfl(olA[j], lane & 48, 64);
        const float lB = __shfl(olB[j], lane & 48, 64);
        const float rA = 1.f / lA, rB = 1.f / lB;
        const long rowA = (long)b * T_SEQ + jA * 64 + wid * 16 + fq * 4 + j;
        const long rowB = (long)b * T_SEQ + jB * 64 + wid * 16 + fq * 4 + j;
#pragma unroll
        for (int nd = 0; nd < 4; ++nd) {
            out[rowA * 1024 + h * 64 + nd * 16 + fr] = (bf16)(oA[nd][j] * rA);
            out[rowB * 1024 + h * 64 + nd * 16 + fr] = (bf16)(oB[nd][j] * rB);
        }
    }
}

// ---------------------------------------------------------------------------
extern "C" void kernel_launch(void* const* d_in, const int* in_sizes, int n_in,
                              void* d_out, int out_size, void* d_ws, size_t ws_size,
                              hipStream_t stream)
{
    const float* x     = (const float*)d_in[0];
    const float* Wq    = (const float*)d_in[1];
    const float* Wk    = (const float*)d_in[2];
    const float* Wv    = (const float*)d_in[3];
    const float* Wproj = (const float*)d_in[4];
    const float* bproj = (const float*)d_in[5];
    const float* W1    = (const float*)d_in[6];
    const float* b1    = (const float*)d_in[7];
    const float* W2    = (const float*)d_in[8];
    const float* b2    = (const float*)d_in[9];
    const float* W3    = (const float*)d_in[10];
    const float* b3    = (const float*)d_in[11];
    const float* ln1g  = (const float*)d_in[12];
    const float* ln1b  = (const float*)d_in[13];
    const float* ln2g  = (const float*)d_in[14];
    const float* ln2b  = (const float*)d_in[15];

    char* ws = (char*)d_ws;
    size_t off = 0;
    auto alloc = [&](size_t bytes) {
        void* p = ws + off;
        off += (bytes + 255) & ~(size_t)255;
        return p;
    };
    bf16* Wqkv_t  = (bf16*)alloc(3072ul * 1024 * 2);
    bf16* Wproj_t = (bf16*)alloc(1024ul * 1024 * 2);
    bf16* W1_t    = (bf16*)alloc(4096ul * 1024 * 2);
    bf16* W2_t    = (bf16*)alloc(4096ul * 4096 * 2);
    bf16* W3_t    = (bf16*)alloc(1024ul * 4096 * 2);
    bf16* hbuf    = (bf16*)alloc(8192ul * 1024 * 2);
    bf16* x1b     = (bf16*)alloc(8192ul * 1024 * 2);   // bf16 residual stream
    bf16* a1      = (bf16*)alloc(8192ul * 4096 * 2);   // also hosts vt pre-FF1
    char* R1      = (char*)alloc(8192ul * 4096 * 2);
    bf16* qkvb    = (bf16*)R1;
    bf16* attnb   = (bf16*)(R1 + 8192ul * 3072 * 2);
    bf16* a2      = (bf16*)R1;
    bf16* vt      = a1;   // [1024][8192] V^T; dead once FF1 writes a1

    hipFuncSetAttribute(reinterpret_cast<const void*>(&gemm256<1>),
                        hipFuncAttributeMaxDynamicSharedMemorySize, 131072);
    hipFuncSetAttribute(reinterpret_cast<const void*>(&gemm256n<0>),
                        hipFuncAttributeMaxDynamicSharedMemorySize, 98304);
    hipFuncSetAttribute(reinterpret_cast<const void*>(&gemm256n<3>),
                        hipFuncAttributeMaxDynamicSharedMemorySize, 98304);
    hipFuncSetAttribute(reinterpret_cast<const void*>(&gemm256n<4>),
                        hipFuncAttributeMaxDynamicSharedMemorySize, 98304);

    const dim3 tb(32, 8);
    transpose_f32_bf16<<<dim3(2, 32, 16), tb, 0, stream>>>(Wq, Wqkv_t,                1024, 64, 1024);
    transpose_f32_bf16<<<dim3(2, 32, 16), tb, 0, stream>>>(Wk, Wqkv_t + 1024l * 1024, 1024, 64, 1024);
    transpose_f32_bf16<<<dim3(2, 32, 16), tb, 0, stream>>>(Wv, Wqkv_t + 2048l * 1024, 1024, 64, 1024);
    transpose_f32_bf16<<<dim3(32, 32, 1),   tb, 0, stream>>>(Wproj, Wproj_t, 1024, 1024, 1024);
    transpose_f32_bf16<<<dim3(128, 32, 1),  tb, 0, stream>>>(W1, W1_t, 1024, 4096, 1024);
    transpose_f32_bf16<<<dim3(128, 128, 1), tb, 0, stream>>>(W2, W2_t, 4096, 4096, 4096);
    transpose_f32_bf16<<<dim3(32, 128, 1),  tb, 0, stream>>>(W3, W3_t, 4096, 1024, 4096);

    ln_kernel<<<8192, 256, 0, stream>>>(x, ln1g, ln1b, hbuf);
    // QKV: 32 x 24 = 768 blocks
    gemm256n<0><<<768, 512, 98304, stream>>>(hbuf, Wqkv_t, nullptr, nullptr, qkvb,
                                             8192, 3072, 1024, 24);
    // V^T: qkvb cols [2048,3072) -> vt [1024][8192]
    transpose_bf16<<<dim3(32, 256), tb, 0, stream>>>(qkvb + 2048, vt, 3072, 8192);
    attn_kernel<<<dim3(16, 16, 4), 256, 0, stream>>>(qkvb, vt, attnb);
    // proj: bias + fp32 resid(x) -> bf16 x1b
    gemm256n<3><<<256, 512, 98304, stream>>>(attnb, Wproj_t, bproj, x, x1b,
                                             8192, 1024, 1024, 8);
    ln_kernel_b<<<8192, 256, 0, stream>>>(x1b, ln2g, ln2b, hbuf);
    // FF1: 512 blocks
    gemm256<1><<<512, 512, 131072, stream>>>(hbuf, W1_t, b1, nullptr, a1,
                                             8192, 4096, 1024, 16);
    // FF2: 512 blocks
    gemm256<1><<<512, 512, 131072, stream>>>(a1, W2_t, b2, nullptr, a2,
                                             8192, 4096, 4096, 16);
    // FF3: bias + bf16 resid(x1b) -> fp32 d_out
    gemm256n<4><<<256, 512, 98304, stream>>>(a2, W3_t, b3, x1b, (float*)d_out,
                                             8192, 1024, 4096, 8);
}

// Round 16
// 650.399 us; speedup vs baseline: 1.1924x; 1.0225x over previous
//
#include <hip/hip_runtime.h>

typedef __bf16 bf16;
typedef bf16  bf16x8 __attribute__((ext_vector_type(8)));
typedef bf16  bf16x4 __attribute__((ext_vector_type(4)));
typedef float f32x4  __attribute__((ext_vector_type(4)));

#define T_SEQ 2048

__device__ __forceinline__ void gload_lds16(const bf16* g, bf16* l) {
    __builtin_amdgcn_global_load_lds(
        (const __attribute__((address_space(1))) unsigned int*)g,
        (__attribute__((address_space(3))) unsigned int*)l,
        16, 0, 0);
}

#define VMCNT(n) asm volatile("s_waitcnt vmcnt(" #n ")" ::: "memory")
#define BAR() do { asm volatile("" ::: "memory"); __builtin_amdgcn_s_barrier(); \
                   asm volatile("" ::: "memory"); } while (0)

// ---------------------------------------------------------------------------
// Tiled transpose fp32 [R][Cc] -> bf16 [Cc][R], batched on z.
// ---------------------------------------------------------------------------
__global__ __launch_bounds__(256) void transpose_f32_bf16(
    const float* __restrict__ in, bf16* __restrict__ out, int R, int Cc, int ldo)
{
    __shared__ float tile[32][33];
    const int bx = blockIdx.x * 32;
    const int by = blockIdx.y * 32;
    const long bi = (long)blockIdx.z * R * Cc;
    const long bo = (long)blockIdx.z * Cc * ldo;
    const int tx = threadIdx.x, ty = threadIdx.y;
#pragma unroll
    for (int i = 0; i < 4; ++i)
        tile[ty + i * 8][tx] = in[bi + (long)(by + ty + i * 8) * Cc + bx + tx];
    __syncthreads();
#pragma unroll
    for (int i = 0; i < 4; ++i)
        out[bo + (long)(bx + ty + i * 8) * ldo + by + tx] = (bf16)tile[tx][ty + i * 8];
}

// ---------------------------------------------------------------------------
// Fused Wq/Wk/Wv transpose: z in [0,48), sel = z/16 picks the weight.
// Reproduces the three separate launches exactly (bo = z * 64 * 1024).
// ---------------------------------------------------------------------------
__global__ __launch_bounds__(256) void transpose_qkv_w(
    const float* __restrict__ Wq, const float* __restrict__ Wk,
    const float* __restrict__ Wv, bf16* __restrict__ out)
{
    __shared__ float tile[32][33];
    const int sel = blockIdx.z >> 4;
    const int zz  = blockIdx.z & 15;
    const float* in = (sel == 0) ? Wq : (sel == 1) ? Wk : Wv;
    const int bx = blockIdx.x * 32;           // col within D=64
    const int by = blockIdx.y * 32;           // row within C=1024
    const long bi = (long)zz * 1024 * 64;
    const long bo = (long)blockIdx.z * 64 * 1024;
    const int tx = threadIdx.x, ty = threadIdx.y;
#pragma unroll
    for (int i = 0; i < 4; ++i)
        tile[ty + i * 8][tx] = in[bi + (long)(by + ty + i * 8) * 64 + bx + tx];
    __syncthreads();
#pragma unroll
    for (int i = 0; i < 4; ++i)
        out[bo + (long)(bx + ty + i * 8) * 1024 + by + tx] = (bf16)tile[tx][ty + i * 8];
}

// ---------------------------------------------------------------------------
// Tiled transpose bf16 [rows][ldi] -> bf16 [cols][ldo] (for V^T).
// ---------------------------------------------------------------------------
__global__ __launch_bounds__(256) void transpose_bf16(
    const bf16* __restrict__ in, bf16* __restrict__ out, int ldi, int ldo)
{
    __shared__ bf16 tile[32][33];
    const int bx = blockIdx.x * 32;
    const int by = blockIdx.y * 32;
    const int tx = threadIdx.x, ty = threadIdx.y;
#pragma unroll
    for (int i = 0; i < 4; ++i)
        tile[ty + i * 8][tx] = in[(long)(by + ty + i * 8) * ldi + bx + tx];
    __syncthreads();
#pragma unroll
    for (int i = 0; i < 4; ++i)
        out[(long)(bx + ty + i * 8) * ldo + by + tx] = tile[tx][ty + i * 8];
}

// ---------------------------------------------------------------------------
// LayerNorm fp32 input -> bf16; and bf16-input variant.
// ---------------------------------------------------------------------------
__global__ __launch_bounds__(256) void ln_kernel(
    const float* __restrict__ x, const float* __restrict__ g,
    const float* __restrict__ bb, bf16* __restrict__ out)
{
    const long row = blockIdx.x;
    const int tid = threadIdx.x;
    const float4 v = ((const float4*)(x + row * 1024))[tid];
    float s  = v.x + v.y + v.z + v.w;
    float s2 = v.x * v.x + v.y * v.y + v.z * v.z + v.w * v.w;
#pragma unroll
    for (int off = 32; off >= 1; off >>= 1) {
        s  += __shfl_xor(s,  off, 64);
        s2 += __shfl_xor(s2, off, 64);
    }
    __shared__ float red[8];
    const int wid = tid >> 6;
    if ((tid & 63) == 0) { red[wid] = s; red[4 + wid] = s2; }
    __syncthreads();
    s  = red[0] + red[1] + red[2] + red[3];
    s2 = red[4] + red[5] + red[6] + red[7];
    const float mu   = s * (1.f / 1024.f);
    const float rstd = rsqrtf(s2 * (1.f / 1024.f) - mu * mu + 1e-5f);
    const float4 gv = ((const float4*)g)[tid];
    const float4 bv = ((const float4*)bb)[tid];
    bf16x4 ov;
    ov[0] = (bf16)((v.x - mu) * rstd * gv.x + bv.x);
    ov[1] = (bf16)((v.y - mu) * rstd * gv.y + bv.y);
    ov[2] = (bf16)((v.z - mu) * rstd * gv.z + bv.z);
    ov[3] = (bf16)((v.w - mu) * rstd * gv.w + bv.w);
    *(bf16x4*)(out + row * 1024 + tid * 4) = ov;
}

__global__ __launch_bounds__(256) void ln_kernel_b(
    const bf16* __restrict__ x, const float* __restrict__ g,
    const float* __restrict__ bb, bf16* __restrict__ out)
{
    const long row = blockIdx.x;
    const int tid = threadIdx.x;
    const bf16x4 vb = ((const bf16x4*)(x + row * 1024))[tid];
    const float v0 = (float)vb[0], v1 = (float)vb[1];
    const float v2 = (float)vb[2], v3 = (float)vb[3];
    float s  = v0 + v1 + v2 + v3;
    float s2 = v0 * v0 + v1 * v1 + v2 * v2 + v3 * v3;
#pragma unroll
    for (int off = 32; off >= 1; off >>= 1) {
        s  += __shfl_xor(s,  off, 64);
        s2 += __shfl_xor(s2, off, 64);
    }
    __shared__ float red[8];
    const int wid = tid >> 6;
    if ((tid & 63) == 0) { red[wid] = s; red[4 + wid] = s2; }
    __syncthreads();
    s  = red[0] + red[1] + red[2] + red[3];
    s2 = red[4] + red[5] + red[6] + red[7];
    const float mu   = s * (1.f / 1024.f);
    const float rstd = rsqrtf(s2 * (1.f / 1024.f) - mu * mu + 1e-5f);
    const float4 gv = ((const float4*)g)[tid];
    const float4 bv = ((const float4*)bb)[tid];
    bf16x4 ov;
    ov[0] = (bf16)((v0 - mu) * rstd * gv.x + bv.x);
    ov[1] = (bf16)((v1 - mu) * rstd * gv.y + bv.y);
    ov[2] = (bf16)((v2 - mu) * rstd * gv.z + bv.z);
    ov[3] = (bf16)((v3 - mu) * rstd * gv.w + bv.w);
    *(bf16x4*)(out + row * 1024 + tid * 4) = ov;
}

// ---------------------------------------------------------------------------
// Shared fragment-load / MFMA macros for the 256-row GEMMs.
// ---------------------------------------------------------------------------
#define LOADA(BUFP, QM) do {                                                   \
    const char* ab_ = (BUFP) + (size_t)((wr * 64 + (QM) * 128 + fr) * 128);    \
    _Pragma("unroll") for (int m_ = 0; m_ < 4; ++m_) {                         \
        af[m_][0] = *(const bf16x8*)(ab_ + m_ * 2048 + so0);                   \
        af[m_][1] = *(const bf16x8*)(ab_ + m_ * 2048 + so1); } } while (0)

#define LOADB(BUFP, QN, DST) do {                                              \
    const char* bb_ = (BUFP) + (size_t)((wc * 32 + (QN) * 128 + fr) * 128);    \
    _Pragma("unroll") for (int n_ = 0; n_ < 2; ++n_) {                         \
        DST[n_][0] = *(const bf16x8*)(bb_ + n_ * 2048 + so0);                  \
        DST[n_][1] = *(const bf16x8*)(bb_ + n_ * 2048 + so1); } } while (0)

#define MMA(ACC, BSET) do { __builtin_amdgcn_s_setprio(1);                     \
    _Pragma("unroll") for (int m_ = 0; m_ < 4; ++m_)                           \
    _Pragma("unroll") for (int n_ = 0; n_ < 2; ++n_) {                         \
        ACC[m_][n_] = __builtin_amdgcn_mfma_f32_16x16x32_bf16(                 \
            af[m_][0], BSET[n_][0], ACC[m_][n_], 0, 0, 0);                     \
        ACC[m_][n_] = __builtin_amdgcn_mfma_f32_16x16x32_bf16(                 \
            af[m_][1], BSET[n_][1], ACC[m_][n_], 0, 0, 0); }                   \
    __builtin_amdgcn_s_setprio(0); } while (0)

// ---------------------------------------------------------------------------
// 256x256 bf16 GEMM (PROVEN): 1.5-tile-ahead pipeline + B0 retention.
// ---------------------------------------------------------------------------
#define TB_DEEP(W1N, W3N, ISSN, ISSC) do {                                     \
    const char* abuf = cAs + ((size_t)cur << 15);                              \
    const char* bbuf = cBs + ((size_t)cur << 15);                              \
    const long kb  = (long)(k + 1) * 64;                                       \
    const long kb2 = (long)(k + 2) * 64;                                       \
    LOADA(abuf, 0);                                                            \
    LOADB(bbuf, 0, bfv0);                                                      \
    if (ISSN) stageB(nxt, 0, kb);        /* B0[k+1] */                         \
    BAR(); MMA(a00, bfv0); BAR();                                              \
    LOADB(bbuf, 1, bfv1);                                                      \
    if (ISSN) stageA(nxt, 1, kb);        /* A1[k+1] */                         \
    VMCNT(W1N);                                                                \
    BAR(); MMA(a01, bfv1); BAR();                                              \
    LOADA(abuf, 1);                                                            \
    if (ISSC) stageA(cur, 0, kb2);       /* A0[k+2] */                         \
    BAR(); MMA(a11, bfv1); BAR();                                              \
    if (ISSC) stageB(cur, 1, kb2);       /* B1[k+2] */                         \
    VMCNT(W3N);                                                                \
    BAR(); MMA(a10, bfv0); BAR(); } while (0)

template <int MODE>
__global__ __launch_bounds__(512, 1) void gemm256(
    const bf16* __restrict__ A, const bf16* __restrict__ Bt,
    const float* __restrict__ bias, const float* __restrict__ resid,
    void* __restrict__ outp, int M, int N, int K, int nbn)
{
    extern __shared__ __align__(16) char smem[];
    char* cAs = smem;
    char* cBs = smem + 65536;

    const int tid = threadIdx.x;
    const int wid = tid >> 6, lane = tid & 63;
    const int wr = wid >> 2, wc = wid & 3;
    const int fr = lane & 15, fq = lane >> 4;

    const int nwg = gridDim.x;
    const int cpx = nwg >> 3;
    const int b0  = blockIdx.x;
    const int bid = (b0 & 7) * cpx + (b0 >> 3);
    const long bm = bid / nbn, bn = bid % nbn;
    const long bmrow = bm * 256, bnrow = bn * 256;

    const int srow0 = wid * 8 + (lane >> 3);
    const int sslot = (lane & 7) ^ (lane >> 3);
    auto stageA = [&](int buf, int h, long kt) {
        const bf16* g = A + (size_t)(bmrow + h * 128 + srow0) * K + kt + sslot * 8;
        char* l = cAs + ((size_t)buf << 15) + h * 16384 + (size_t)wid * 1024;
        gload_lds16(g, (bf16*)l);
        gload_lds16(g + (size_t)64 * K, (bf16*)(l + 8192));
    };
    auto stageB = [&](int buf, int h, long kt) {
        const bf16* g = Bt + (size_t)(bnrow + h * 128 + srow0) * K + kt + sslot * 8;
        char* l = cBs + ((size_t)buf << 15) + h * 16384 + (size_t)wid * 1024;
        gload_lds16(g, (bf16*)l);
        gload_lds16(g + (size_t)64 * K, (bf16*)(l + 8192));
    };

    const int sx  = fr & 7;
    const int so0 = ((fq) ^ sx) * 16;
    const int so1 = ((4 + fq) ^ sx) * 16;

    bf16x8 af[4][2], bfv0[2][2], bfv1[2][2];
    f32x4 a00[4][2], a01[4][2], a11[4][2], a10[4][2];
#pragma unroll
    for (int m = 0; m < 4; ++m)
#pragma unroll
        for (int n = 0; n < 2; ++n) {
            a00[m][n] = {0.f, 0.f, 0.f, 0.f}; a01[m][n] = {0.f, 0.f, 0.f, 0.f};
            a11[m][n] = {0.f, 0.f, 0.f, 0.f}; a10[m][n] = {0.f, 0.f, 0.f, 0.f};
        }

    stageA(0, 0, 0);      // A0_0
    stageB(0, 1, 0);      // B1_0
    stageB(0, 0, 0);      // B0_0
    stageA(0, 1, 0);      // A1_0
    stageA(1, 0, 64);     // A0_1
    stageB(1, 1, 64);     // B1_1
    VMCNT(6);
    BAR();

    const int NT = K >> 6;
    int cur, nxt;
    int k = 0;
    for (; k < NT - 2; ++k) {
        cur = k & 1; nxt = cur ^ 1;
        TB_DEEP(8, 6, true, true);
    }
    cur = k & 1; nxt = cur ^ 1;
    TB_DEEP(8, 2, true, false);          // k = NT-2
    ++k;
    cur = k & 1; nxt = cur ^ 1;
    TB_DEEP(0, 0, false, false);         // k = NT-1

    auto writeQ = [&](f32x4 (&acc)[4][2], int QM, int QN) {
#pragma unroll
        for (int m = 0; m < 4; ++m) {
            const long row0 = bmrow + wr * 64 + QM * 128 + m * 16 + fq * 4;
#pragma unroll
            for (int n = 0; n < 2; ++n) {
                const long col = bnrow + wc * 32 + QN * 128 + n * 16 + fr;
                const float bv = (MODE == 0) ? 0.f : bias[col];
#pragma unroll
                for (int j = 0; j < 4; ++j) {
                    const long row = row0 + j;
                    float v = acc[m][n][j] + bv;
                    if (MODE == 1) v = fmaxf(v, 0.f);
                    if (MODE == 2) {
                        v += resid[row * N + col];
                        ((float*)outp)[row * N + col] = v;
                    } else {
                        ((bf16*)outp)[row * N + col] = (bf16)v;
                    }
                }
            }
        }
    };
    writeQ(a00, 0, 0); writeQ(a01, 0, 1); writeQ(a11, 1, 1); writeQ(a10, 1, 0);
}

// ---------------------------------------------------------------------------
// 256x128 bf16 GEMM (PROVEN schedule). MODE: 0 plain->bf16;
// 3 bias+f32resid->bf16; 4 bias+bf16resid->f32.
// ---------------------------------------------------------------------------
#define TILE_BODY_N(PRE, LAST) do {                                            \
    const char* abuf = cAs + ((size_t)cur << 15);                              \
    const char* bbuf = cBs + ((size_t)cur << 14);                              \
    const long kn = (long)(k + 1) * 64;                                        \
    LOADA(abuf, 0);                                                            \
    LOADB(bbuf, 0, bfv);                                                       \
    if (PRE) { stageA(nxt, 0, kn); stageB(nxt, kn); stageA(nxt, 1, kn);        \
               VMCNT(6); }                                                     \
    else     { VMCNT(0); }                                                     \
    BAR(); MMA(aq0, bfv); BAR();                                               \
    LOADA(abuf, 1);                                                            \
    if (PRE) { VMCNT(2); }                                                     \
    if (!LAST) { BAR(); }                                                      \
    MMA(aq1, bfv);                                                             \
    if (!LAST) { BAR(); } } while (0)

template <int MODE>
__global__ __launch_bounds__(512, 2) void gemm256n(
    const bf16* __restrict__ A, const bf16* __restrict__ Bt,
    const float* __restrict__ bias, const void* __restrict__ resid,
    void* __restrict__ outp, int M, int N, int K, int nbn)
{
    extern __shared__ __align__(16) char smem[];
    char* cAs = smem;            // 2 x 32 KiB
    char* cBs = smem + 65536;    // 2 x 16 KiB

    const int tid = threadIdx.x;
    const int wid = tid >> 6, lane = tid & 63;
    const int wr = wid >> 2, wc = wid & 3;
    const int fr = lane & 15, fq = lane >> 4;

    const int nwg = gridDim.x;
    const int cpx = nwg >> 3;
    const int b0  = blockIdx.x;
    const int bid = (b0 & 7) * cpx + (b0 >> 3);
    const long bm = bid / nbn, bn = bid % nbn;
    const long bmrow = bm * 256, bnrow = bn * 128;

    const int srow0 = wid * 8 + (lane >> 3);
    const int sslot = (lane & 7) ^ (lane >> 3);
    auto stageA = [&](int buf, int h, long kt) {
        const bf16* g = A + (size_t)(bmrow + h * 128 + srow0) * K + kt + sslot * 8;
        char* l = cAs + ((size_t)buf << 15) + h * 16384 + (size_t)wid * 1024;
        gload_lds16(g, (bf16*)l);
        gload_lds16(g + (size_t)64 * K, (bf16*)(l + 8192));
    };
    auto stageB = [&](int buf, long kt) {
        const bf16* g = Bt + (size_t)(bnrow + srow0) * K + kt + sslot * 8;
        char* l = cBs + ((size_t)buf << 14) + (size_t)wid * 1024;
        gload_lds16(g, (bf16*)l);
        gload_lds16(g + (size_t)64 * K, (bf16*)(l + 8192));
    };

    const int sx  = fr & 7;
    const int so0 = ((fq) ^ sx) * 16;
    const int so1 = ((4 + fq) ^ sx) * 16;

    bf16x8 af[4][2], bfv[2][2];
    f32x4 aq0[4][2], aq1[4][2];
#pragma unroll
    for (int m = 0; m < 4; ++m)
#pragma unroll
        for (int n = 0; n < 2; ++n) {
            aq0[m][n] = {0.f, 0.f, 0.f, 0.f};
            aq1[m][n] = {0.f, 0.f, 0.f, 0.f};
        }

    stageA(0, 0, 0); stageB(0, 0); stageA(0, 1, 0);
    VMCNT(2);
    BAR();

    const int NT = K >> 6;
    int cur = 0, nxt = 1;
    int k = 0;
    for (; k < NT - 1; ++k) {
        cur = k & 1; nxt = cur ^ 1;
        TILE_BODY_N(true, false);
    }
    cur = k & 1; nxt = cur ^ 1;
    TILE_BODY_N(false, true);

    auto writeQ = [&](f32x4 (&acc)[4][2], int QM) {
#pragma unroll
        for (int m = 0; m < 4; ++m) {
            const long row0 = bmrow + wr * 64 + QM * 128 + m * 16 + fq * 4;
#pragma unroll
            for (int n = 0; n < 2; ++n) {
                const long col = bnrow + wc * 32 + n * 16 + fr;
                const float bv = (MODE == 0) ? 0.f : bias[col];
#pragma unroll
                for (int j = 0; j < 4; ++j) {
                    const long row = row0 + j;
                    float v = acc[m][n][j] + bv;
                    if (MODE == 3) {
                        v += ((const float*)resid)[row * N + col];
                        ((bf16*)outp)[row * N + col] = (bf16)v;
                    } else if (MODE == 4) {
                        v += (float)((const bf16*)resid)[row * N + col];
                        ((float*)outp)[row * N + col] = v;
                    } else {
                        ((bf16*)outp)[row * N + col] = (bf16)v;
                    }
                }
            }
        }
    };
    writeQ(aq0, 0); writeQ(aq1, 1);
}

// ---------------------------------------------------------------------------
// Flash attention (round-9 PROVEN) + XCD-chunked block swizzle: the 16
// pair-blocks of each (h,b) land on ONE XCD so K/V stay in its L2.
// ---------------------------------------------------------------------------
__device__ __forceinline__ void sm_part(
    f32x4* s, float* mj, f32x4* o, f32x4& o_l, bf16* Pp,
    int fr, int fq, int qloc, bool diag)
{
    float v[4][4], mxj[4];
#pragma unroll
    for (int j = 0; j < 4; ++j) {
        const int qg = qloc + fq * 4 + j;
        v[0][j] = s[0][j] * 0.03125f;
        v[1][j] = s[1][j] * 0.03125f;
        v[2][j] = s[2][j] * 0.03125f;
        v[3][j] = s[3][j] * 0.03125f;
        if (diag) {
            if (fr      > qg) v[0][j] = -1e30f;
            if (16 + fr > qg) v[1][j] = -1e30f;
            if (32 + fr > qg) v[2][j] = -1e30f;
            if (48 + fr > qg) v[3][j] = -1e30f;
        }
        float mx = fmaxf(fmaxf(v[0][j], v[1][j]), fmaxf(v[2][j], v[3][j]));
#pragma unroll
        for (int off = 1; off <= 8; off <<= 1) mx = fmaxf(mx, __shfl_xor(mx, off, 16));
        mxj[j] = mx;
    }
    float need = fmaxf(fmaxf(mxj[0] - mj[0], mxj[1] - mj[1]),
                       fmaxf(mxj[2] - mj[2], mxj[3] - mj[3]));
    if (__any(need > 8.f)) {
#pragma unroll
        for (int j = 0; j < 4; ++j) {
            const float mn   = fmaxf(mj[j], mxj[j]);
            const float corr = __expf(mj[j] - mn);
            mj[j] = mn;
#pragma unroll
            for (int nd = 0; nd < 4; ++nd) o[nd][j] *= corr;
            o_l[j] *= corr;
        }
    }
#pragma unroll
    for (int j = 0; j < 4; ++j) {
        bf16* prow = Pp + (fq * 4 + j) * 72;
        prow[fr]      = (bf16)__expf(v[0][j] - mj[j]);
        prow[16 + fr] = (bf16)__expf(v[1][j] - mj[j]);
        prow[32 + fr] = (bf16)__expf(v[2][j] - mj[j]);
        prow[48 + fr] = (bf16)__expf(v[3][j] - mj[j]);
    }
}

__device__ __forceinline__ void attn_step(
    const bf16* __restrict__ Ks, const bf16* __restrict__ Vt,
    bf16* __restrict__ Pp, const bf16x8* qf,
    f32x4* o, f32x4& o_l, float* mj, const bf16x8 onesf,
    int fr, int fq, int qloc, bool diag)
{
    f32x4 s[4];
#pragma unroll
    for (int n = 0; n < 4; ++n) s[n] = {0.f, 0.f, 0.f, 0.f};
    __builtin_amdgcn_s_setprio(1);
#pragma unroll
    for (int n = 0; n < 4; ++n) {
        const int t  = n * 16 + fr;
        const int sw = ((t ^ (t >> 3)) & 7) << 4;
        const bf16x8 kf0 = *(const bf16x8*)((const char*)Ks + t * 128 + ((fq * 16) ^ sw));
        const bf16x8 kf1 = *(const bf16x8*)((const char*)Ks + t * 128 + ((64 + fq * 16) ^ sw));
        s[n] = __builtin_amdgcn_mfma_f32_16x16x32_bf16(qf[0], kf0, s[n], 0, 0, 0);
        s[n] = __builtin_amdgcn_mfma_f32_16x16x32_bf16(qf[1], kf1, s[n], 0, 0, 0);
    }
    __builtin_amdgcn_s_setprio(0);
    sm_part(s, mj, o, o_l, Pp, fr, fq, qloc, diag);
    asm volatile("s_waitcnt lgkmcnt(0)" ::: "memory");
    __builtin_amdgcn_sched_barrier(0);
    const bf16x8 pf0 = *(const bf16x8*)(Pp + fr * 72 + fq * 8);
    const bf16x8 pf1 = *(const bf16x8*)(Pp + fr * 72 + 32 + fq * 8);
    __builtin_amdgcn_s_setprio(1);
#pragma unroll
    for (int nd = 0; nd < 4; ++nd) {
        const int dd = nd * 16 + fr;
        const int sw = ((dd ^ (dd >> 3)) & 7) << 4;
        const bf16x8 vf0 = *(const bf16x8*)((const char*)Vt + dd * 128 + ((fq * 16) ^ sw));
        const bf16x8 vf1 = *(const bf16x8*)((const char*)Vt + dd * 128 + ((64 + fq * 16) ^ sw));
        o[nd] = __builtin_amdgcn_mfma_f32_16x16x32_bf16(pf0, vf0, o[nd], 0, 0, 0);
        o[nd] = __builtin_amdgcn_mfma_f32_16x16x32_bf16(pf1, vf1, o[nd], 0, 0, 0);
    }
    o_l = __builtin_amdgcn_mfma_f32_16x16x32_bf16(pf0, onesf, o_l, 0, 0, 0);
    o_l = __builtin_amdgcn_mfma_f32_16x16x32_bf16(pf1, onesf, o_l, 0, 0, 0);
    __builtin_amdgcn_s_setprio(0);
}

__device__ __forceinline__ void attn_step2(
    const bf16* __restrict__ Ks, const bf16* __restrict__ Vt,
    bf16* __restrict__ PpA, bf16* __restrict__ PpB,
    const bf16x8* qfA, const bf16x8* qfB,
    f32x4* oA, f32x4& olA, float* mA,
    f32x4* oB, f32x4& olB, float* mB,
    const bf16x8 onesf, int fr, int fq, int qloc, bool diagA)
{
    f32x4 sA[4], sB[4];
#pragma unroll
    for (int n = 0; n < 4; ++n) { sA[n] = {0.f, 0.f, 0.f, 0.f}; sB[n] = {0.f, 0.f, 0.f, 0.f}; }
    __builtin_amdgcn_s_setprio(1);
#pragma unroll
    for (int n = 0; n < 4; ++n) {
        const int t  = n * 16 + fr;
        const int sw = ((t ^ (t >> 3)) & 7) << 4;
        const bf16x8 kf0 = *(const bf16x8*)((const char*)Ks + t * 128 + ((fq * 16) ^ sw));
        const bf16x8 kf1 = *(const bf16x8*)((const char*)Ks + t * 128 + ((64 + fq * 16) ^ sw));
        sA[n] = __builtin_amdgcn_mfma_f32_16x16x32_bf16(qfA[0], kf0, sA[n], 0, 0, 0);
        sA[n] = __builtin_amdgcn_mfma_f32_16x16x32_bf16(qfA[1], kf1, sA[n], 0, 0, 0);
        sB[n] = __builtin_amdgcn_mfma_f32_16x16x32_bf16(qfB[0], kf0, sB[n], 0, 0, 0);
        sB[n] = __builtin_amdgcn_mfma_f32_16x16x32_bf16(qfB[1], kf1, sB[n], 0, 0, 0);
    }
    __builtin_amdgcn_s_setprio(0);
    sm_part(sA, mA, oA, olA, PpA, fr, fq, qloc, diagA);
    sm_part(sB, mB, oB, olB, PpB, fr, fq, qloc, false);
    asm volatile("s_waitcnt lgkmcnt(0)" ::: "memory");
    __builtin_amdgcn_sched_barrier(0);
    const bf16x8 pfA0 = *(const bf16x8*)(PpA + fr * 72 + fq * 8);
    const bf16x8 pfA1 = *(const bf16x8*)(PpA + fr * 72 + 32 + fq * 8);
    const bf16x8 pfB0 = *(const bf16x8*)(PpB + fr * 72 + fq * 8);
    const bf16x8 pfB1 = *(const bf16x8*)(PpB + fr * 72 + 32 + fq * 8);
    __builtin_amdgcn_s_setprio(1);
#pragma unroll
    for (int nd = 0; nd < 4; ++nd) {
        const int dd = nd * 16 + fr;
        const int sw = ((dd ^ (dd >> 3)) & 7) << 4;
        const bf16x8 vf0 = *(const bf16x8*)((const char*)Vt + dd * 128 + ((fq * 16) ^ sw));
        const bf16x8 vf1 = *(const bf16x8*)((const char*)Vt + dd * 128 + ((64 + fq * 16) ^ sw));
        oA[nd] = __builtin_amdgcn_mfma_f32_16x16x32_bf16(pfA0, vf0, oA[nd], 0, 0, 0);
        oA[nd] = __builtin_amdgcn_mfma_f32_16x16x32_bf16(pfA1, vf1, oA[nd], 0, 0, 0);
        oB[nd] = __builtin_amdgcn_mfma_f32_16x16x32_bf16(pfB0, vf0, oB[nd], 0, 0, 0);
        oB[nd] = __builtin_amdgcn_mfma_f32_16x16x32_bf16(pfB1, vf1, oB[nd], 0, 0, 0);
    }
    olA = __builtin_amdgcn_mfma_f32_16x16x32_bf16(pfA0, onesf, olA, 0, 0, 0);
    olA = __builtin_amdgcn_mfma_f32_16x16x32_bf16(pfA1, onesf, olA, 0, 0, 0);
    olB = __builtin_amdgcn_mfma_f32_16x16x32_bf16(pfB0, onesf, olB, 0, 0, 0);
    olB = __builtin_amdgcn_mfma_f32_16x16x32_bf16(pfB1, onesf, olB, 0, 0, 0);
    __builtin_amdgcn_s_setprio(0);
}

__global__ __launch_bounds__(256) void attn_kernel(
    const bf16* __restrict__ qkv, const bf16* __restrict__ vt,
    bf16* __restrict__ out)
{
    // XCD-chunked bijective swizzle (1024 blocks, 1024 % 8 == 0):
    // each XCD owns 128 consecutive wgids = 8 complete (h,b) groups.
    const int bidx = blockIdx.x;
    const int wgid = ((bidx & 7) << 7) + (bidx >> 3);
    const int pair = wgid & 15;
    const int h    = (wgid >> 4) & 15;
    const int b    = wgid >> 8;
    const int tid = threadIdx.x, wid = tid >> 6, lane = tid & 63;
    const int fr = lane & 15, fq = lane >> 4;
    const int jA = pair, jB = 31 - pair;
    const bf16* baseQ = qkv + ((long)b * T_SEQ) * 3072 + h * 64;
    const bf16* baseK = baseQ + 1024;
    const bf16* baseV = vt + (long)(h * 64) * 8192 + (long)b * T_SEQ;

    __shared__ __align__(16) bf16 Ks[2][64 * 64];
    __shared__ __align__(16) bf16 Vs[2][64 * 64];
    __shared__ __align__(16) bf16 Plds[2][4][16 * 72];

    const int qrA = jA * 64 + wid * 16 + fr;
    const int qrB = jB * 64 + wid * 16 + fr;
    bf16x8 qfA[2], qfB[2];
#pragma unroll
    for (int kk = 0; kk < 2; ++kk) {
        qfA[kk] = *(const bf16x8*)(baseQ + (long)qrA * 3072 + kk * 32 + fq * 8);
        qfB[kk] = *(const bf16x8*)(baseQ + (long)qrB * 3072 + kk * 32 + fq * 8);
    }

    bf16x8 onesf;
    {
        const bf16 ov = (fr == 0) ? (bf16)1.f : (bf16)0.f;
#pragma unroll
        for (int e = 0; e < 8; ++e) onesf[e] = ov;
    }

    f32x4 oA[4], oB[4], olA, olB;
    float mA[4], mB[4];
#pragma unroll
    for (int nd = 0; nd < 4; ++nd) { oA[nd] = {0.f, 0.f, 0.f, 0.f}; oB[nd] = {0.f, 0.f, 0.f, 0.f}; }
    olA = {0.f, 0.f, 0.f, 0.f}; olB = {0.f, 0.f, 0.f, 0.f};
#pragma unroll
    for (int j = 0; j < 4; ++j) { mA[j] = -1e30f; mB[j] = -1e30f; }

    const int t_p0 = wid * 16 + (lane >> 3);
    const int t_p1 = t_p0 + 8;
    const int kcb0 = ((lane & 7) * 16) ^ (((t_p0 ^ (t_p0 >> 3)) & 7) << 4);
    const int kcb1 = ((lane & 7) * 16) ^ (((t_p1 ^ (t_p1 >> 3)) & 7) << 4);

    bf16* PA = &Plds[0][wid][0];
    bf16* PB = &Plds[1][wid][0];

    auto stage = [&](int buf, int c) {
        const long s0 = (long)c * 64;
        gload_lds16(baseK + (s0 + t_p0) * 3072 + (kcb0 >> 1), &Ks[buf][(wid * 2) * 512]);
        gload_lds16(baseK + (s0 + t_p1) * 3072 + (kcb1 >> 1), &Ks[buf][(wid * 2 + 1) * 512]);
        gload_lds16(baseV + (long)t_p0 * 8192 + s0 + (kcb0 >> 1), &Vs[buf][(wid * 2) * 512]);
        gload_lds16(baseV + (long)t_p1 * 8192 + s0 + (kcb1 >> 1), &Vs[buf][(wid * 2 + 1) * 512]);
    };

    const int nch = jB + 1;
    stage(0, 0);
    for (int c = 0; c < nch; ++c) {
        const int cur = c & 1;
        if (c + 1 < nch) { stage(cur ^ 1, c + 1); VMCNT(4); }
        else             { VMCNT(0); }
        BAR();
        if (c <= jA)
            attn_step2(Ks[cur], Vs[cur], PA, PB, qfA, qfB,
                       oA, olA, mA, oB, olB, mB, onesf, fr, fq, wid * 16, c == jA);
        else
            attn_step(Ks[cur], Vs[cur], PB, qfB, oB, olB, mB, onesf,
                      fr, fq, wid * 16, c == jB);
        BAR();
    }

#pragma unroll
    for (int j = 0; j < 4; ++j) {
        const float lA = __shfl(olA[j], lane & 48, 64);
        const float lB = __shfl(olB[j], lane & 48, 64);
        const float rA = 1.f / lA, rB = 1.f / lB;
        const long rowA = (long)b * T_SEQ + jA * 64 + wid * 16 + fq * 4 + j;
        const long rowB = (long)b * T_SEQ + jB * 64 + wid * 16 + fq * 4 + j;
#pragma unroll
        for (int nd = 0; nd < 4; ++nd) {
            out[rowA * 1024 + h * 64 + nd * 16 + fr] = (bf16)(oA[nd][j] * rA);
            out[rowB * 1024 + h * 64 + nd * 16 + fr] = (bf16)(oB[nd][j] * rB);
        }
    }
}

// ---------------------------------------------------------------------------
extern "C" void kernel_launch(void* const* d_in, const int* in_sizes, int n_in,
                              void* d_out, int out_size, void* d_ws, size_t ws_size,
                              hipStream_t stream)
{
    const float* x     = (const float*)d_in[0];
    const float* Wq    = (const float*)d_in[1];
    const float* Wk    = (const float*)d_in[2];
    const float* Wv    = (const float*)d_in[3];
    const float* Wproj = (const float*)d_in[4];
    const float* bproj = (const float*)d_in[5];
    const float* W1    = (const float*)d_in[6];
    const float* b1    = (const float*)d_in[7];
    const float* W2    = (const float*)d_in[8];
    const float* b2    = (const float*)d_in[9];
    const float* W3    = (const float*)d_in[10];
    const float* b3    = (const float*)d_in[11];
    const float* ln1g  = (const float*)d_in[12];
    const float* ln1b  = (const float*)d_in[13];
    const float* ln2g  = (const float*)d_in[14];
    const float* ln2b  = (const float*)d_in[15];

    char* ws = (char*)d_ws;
    size_t off = 0;
    auto alloc = [&](size_t bytes) {
        void* p = ws + off;
        off += (bytes + 255) & ~(size_t)255;
        return p;
    };
    bf16* Wqkv_t  = (bf16*)alloc(3072ul * 1024 * 2);
    bf16* Wproj_t = (bf16*)alloc(1024ul * 1024 * 2);
    bf16* W1_t    = (bf16*)alloc(4096ul * 1024 * 2);
    bf16* W2_t    = (bf16*)alloc(4096ul * 4096 * 2);
    bf16* W3_t    = (bf16*)alloc(1024ul * 4096 * 2);
    bf16* hbuf    = (bf16*)alloc(8192ul * 1024 * 2);
    bf16* x1b     = (bf16*)alloc(8192ul * 1024 * 2);   // bf16 residual stream
    bf16* a1      = (bf16*)alloc(8192ul * 4096 * 2);   // also hosts vt pre-FF1
    char* R1      = (char*)alloc(8192ul * 4096 * 2);
    bf16* qkvb    = (bf16*)R1;
    bf16* attnb   = (bf16*)(R1 + 8192ul * 3072 * 2);
    bf16* a2      = (bf16*)R1;
    bf16* vt      = a1;   // [1024][8192] V^T; dead once FF1 writes a1

    hipFuncSetAttribute(reinterpret_cast<const void*>(&gemm256<1>),
                        hipFuncAttributeMaxDynamicSharedMemorySize, 131072);
    hipFuncSetAttribute(reinterpret_cast<const void*>(&gemm256n<0>),
                        hipFuncAttributeMaxDynamicSharedMemorySize, 98304);
    hipFuncSetAttribute(reinterpret_cast<const void*>(&gemm256n<3>),
                        hipFuncAttributeMaxDynamicSharedMemorySize, 98304);
    hipFuncSetAttribute(reinterpret_cast<const void*>(&gemm256n<4>),
                        hipFuncAttributeMaxDynamicSharedMemorySize, 98304);

    const dim3 tb(32, 8);
    // fused Wq/Wk/Wv transpose (one launch instead of three)
    transpose_qkv_w<<<dim3(2, 32, 48), tb, 0, stream>>>(Wq, Wk, Wv, Wqkv_t);
    transpose_f32_bf16<<<dim3(32, 32, 1),   tb, 0, stream>>>(Wproj, Wproj_t, 1024, 1024, 1024);
    transpose_f32_bf16<<<dim3(128, 32, 1),  tb, 0, stream>>>(W1, W1_t, 1024, 4096, 1024);
    transpose_f32_bf16<<<dim3(128, 128, 1), tb, 0, stream>>>(W2, W2_t, 4096, 4096, 4096);
    transpose_f32_bf16<<<dim3(32, 128, 1),  tb, 0, stream>>>(W3, W3_t, 4096, 1024, 4096);

    ln_kernel<<<8192, 256, 0, stream>>>(x, ln1g, ln1b, hbuf);
    // QKV: 32 x 24 = 768 blocks
    gemm256n<0><<<768, 512, 98304, stream>>>(hbuf, Wqkv_t, nullptr, nullptr, qkvb,
                                             8192, 3072, 1024, 24);
    // V^T: qkvb cols [2048,3072) -> vt [1024][8192]
    transpose_bf16<<<dim3(32, 256), tb, 0, stream>>>(qkvb + 2048, vt, 3072, 8192);
    // attention: 1024 blocks, XCD-chunked swizzle for K/V L2 locality
    attn_kernel<<<1024, 256, 0, stream>>>(qkvb, vt, attnb);
    // proj: bias + fp32 resid(x) -> bf16 x1b
    gemm256n<3><<<256, 512, 98304, stream>>>(attnb, Wproj_t, bproj, x, x1b,
                                             8192, 1024, 1024, 8);
    ln_kernel_b<<<8192, 256, 0, stream>>>(x1b, ln2g, ln2b, hbuf);
    // FF1: 512 blocks
    gemm256<1><<<512, 512, 131072, stream>>>(hbuf, W1_t, b1, nullptr, a1,
                                             8192, 4096, 1024, 16);
    // FF2: 512 blocks
    gemm256<1><<<512, 512, 131072, stream>>>(a1, W2_t, b2, nullptr, a2,
                                             8192, 4096, 4096, 16);
    // FF3: bias + bf16 resid(x1b) -> fp32 d_out
    gemm256n<4><<<256, 512, 98304, stream>>>(a2, W3_t, b3, x1b, (float*)d_out,
                                             8192, 1024, 4096, 8);
}